// Round 1
// baseline (1454.365 us; speedup 1.0000x reference)
//
#include <hip/hip_runtime.h>
#include <stdint.h>

typedef unsigned short u16;
typedef uint32_t u32;

typedef __bf16 bf16x8 __attribute__((ext_vector_type(8)));
typedef float f32x4 __attribute__((ext_vector_type(4)));

union B8 { uint4 q; u32 u[4]; bf16x8 v; };

__device__ __forceinline__ u16 f2bf(float f) {
  u32 u = __float_as_uint(f);
  u32 r = (u + 0x7fffu + ((u >> 16) & 1u)) >> 16;
  return (u16)r;
}
__device__ __forceinline__ float bflo(u32 p) { return __uint_as_float(p << 16); }
__device__ __forceinline__ float bfhi(u32 p) { return __uint_as_float(p & 0xffff0000u); }
__device__ __forceinline__ float sigf(float x) { return 1.f / (1.f + __expf(-x)); }

// ---------------- prep: pack/convert all weights ----------------
__global__ __launch_bounds__(256) void prep_k(
    const float* rnn_w_hh, const float* dec_w_hh, const float* conv1_w,
    const float* conv2_w, const float* rnn_w_ih, const float* dec_w_ih,
    const float* fc_w, const float* emb, const int* y,
    u32* wT2e, u32* wT2d, u16* w1b, u16* w2b, u16* wihb, u16* dwihb,
    u16* fcwb, u16* adec)
{
  int e = blockIdx.x * 256 + threadIdx.x;
  const int S0 = 24576, S1 = 24576, S2 = 5120, S3 = 163840, S4 = 208896,
            S5 = 12288, S6 = 524288, S7 = 130048;
  if (e < S0) { int k2 = e / 384, g = e - k2 * 384;
    wT2e[e] = (u32)f2bf(rnn_w_hh[g*128 + 2*k2]) | ((u32)f2bf(rnn_w_hh[g*128 + 2*k2 + 1]) << 16);
    return; }
  e -= S0;
  if (e < S1) { int k2 = e / 384, g = e - k2 * 384;
    wT2d[e] = (u32)f2bf(dec_w_hh[g*128 + 2*k2]) | ((u32)f2bf(dec_w_hh[g*128 + 2*k2 + 1]) << 16);
    return; }
  e -= S1;
  if (e < S2) { int kh = e >> 10, c = (e >> 5) & 31, kw = e & 31;
    w1b[e] = f2bf(conv1_w[c*160 + kh*32 + kw]); return; }
  e -= S2;
  if (e < S3) { int kt = e >> 10, c = (e >> 5) & 31, kw = e & 31;
    int ic = kt / 5, kh = kt - ic * 5;
    w2b[e] = f2bf(conv2_w[((c*32 + ic)*5 + kh)*32 + kw]); return; }
  e -= S3;
  if (e < S4) { wihb[e] = f2bf(rnn_w_ih[e]); return; }
  e -= S4;
  if (e < S5) { dwihb[e] = f2bf(dec_w_ih[e]); return; }
  e -= S5;
  if (e < S6) { fcwb[e] = f2bf(fc_w[e]); return; }
  e -= S6;
  if (e < S7) { int m = e >> 5, k = e & 31;
    int b = m / 127, t = m - b * 127;
    adec[e] = f2bf(emb[y[b*128 + t]*32 + k]); return; }
}

// ---------------- conv1: (32,1,512,161) -> (32,32,254,65), MFMA ----------------
__global__ __launch_bounds__(256) void conv1_k(const float* x, const u16* w1b,
                                               const float* c1b, u16* in1b)
{
  __shared__ __align__(16) u16 slab[35 * 162];
  __shared__ __align__(16) u16 wl[5120];
  int b = blockIdx.x >> 4;
  int oh0 = (blockIdx.x & 15) * 16;
  int ih0 = oh0 * 2;
  for (int e = threadIdx.x; e < 35 * 161; e += 256) {
    int r = e / 161, iw = e - r * 161;
    int ih = ih0 + r;
    float v = (ih < 512) ? x[(b*512 + ih)*161 + iw] : 0.f;
    slab[r*162 + iw] = f2bf(v);
  }
  for (int e = threadIdx.x; e < 5120; e += 256) wl[e] = w1b[e];
  __syncthreads();
  int lane = threadIdx.x & 63, wid = threadIdx.x >> 6;
  int lrow = lane & 15, lk = (lane >> 4) * 8;
  B8 bw[5][2];
  #pragma unroll
  for (int kt = 0; kt < 5; kt++)
    #pragma unroll
    for (int ct = 0; ct < 2; ct++)
      bw[kt][ct].q = *(const uint4*)&wl[(kt*32 + ct*16 + lrow)*32 + lk];
  float bias0 = c1b[lrow], bias1 = c1b[16 + lrow];
  for (int mt = wid; mt < 65; mt += 4) {
    int m = mt * 16 + lrow;
    int ohl = m / 65, ow = m - ohl * 65;
    int ro = ohl * 324 + ow * 2 + lk;
    f32x4 a0, a1;
    #pragma unroll
    for (int i = 0; i < 4; i++) { a0[i] = 0.f; a1[i] = 0.f; }
    #pragma unroll
    for (int kt = 0; kt < 5; kt++) {
      B8 af;
      const u32* p = (const u32*)&slab[ro + kt * 162];
      af.u[0] = p[0]; af.u[1] = p[1]; af.u[2] = p[2]; af.u[3] = p[3];
      a0 = __builtin_amdgcn_mfma_f32_16x16x32_bf16(af.v, bw[kt][0].v, a0, 0, 0, 0);
      a1 = __builtin_amdgcn_mfma_f32_16x16x32_bf16(af.v, bw[kt][1].v, a1, 0, 0, 0);
    }
    int rb = mt * 16 + (lane >> 4) * 4;
    #pragma unroll
    for (int i = 0; i < 4; i++) {
      int mr = rb + i;
      int ohl2 = mr / 65, ow2 = mr - ohl2 * 65;
      int oh = oh0 + ohl2;
      if (oh < 254) {
        float v0 = fmaxf(a0[i] + bias0, 0.f);
        float v1 = fmaxf(a1[i] + bias1, 0.f);
        in1b[((b*32 + lrow)*254 + oh)*65 + ow2] = f2bf(v0);
        in1b[((b*32 + 16 + lrow)*254 + oh)*65 + ow2] = f2bf(v1);
      }
    }
  }
}

// ---------------- conv2: (32,32,254,65) -> h (32,125,544) bf16, MFMA ----------------
__global__ __launch_bounds__(256) void conv2_k(const u16* in1b, const u16* w2b,
                                               const float* c2b, u16* hbf)
{
  extern __shared__ char smem[];
  u16* slab = (u16*)smem;              // [32][19][66]  = 80256 B
  u16* wl = (u16*)(smem + 80256);      // [32][32][32]  = 65536 B
  int b = blockIdx.x >> 4;
  int oh0 = (blockIdx.x & 15) * 8;
  int ih0 = oh0 * 2;
  for (int e = threadIdx.x; e < 32 * 19 * 65; e += 256) {
    int ic = e / (19 * 65);
    int rem = e - ic * (19 * 65);
    int r = rem / 65, iw = rem - r * 65;
    int ih = ih0 + r;
    u16 v = (ih < 254) ? in1b[((b*32 + ic)*254 + ih)*65 + iw] : (u16)0;
    slab[(ic*19 + r)*66 + iw] = v;
  }
  int lane = threadIdx.x & 63, wid = threadIdx.x >> 6;
  int lrow = lane & 15, lk = (lane >> 4) * 8;
  int ohl_[3], ow_[3];
  #pragma unroll
  for (int q = 0; q < 3; q++) {
    int mt = (q == 2) ? 8 : (wid + q * 4);
    int m = mt * 16 + lrow;
    if (m > 135) m = 0;
    ohl_[q] = m / 17; ow_[q] = m - ohl_[q] * 17;
  }
  f32x4 acc[3][2];
  #pragma unroll
  for (int q = 0; q < 3; q++)
    #pragma unroll
    for (int ct = 0; ct < 2; ct++)
      #pragma unroll
      for (int i = 0; i < 4; i++) acc[q][ct][i] = 0.f;

  for (int ph = 0; ph < 5; ph++) {
    __syncthreads();
    for (int e = threadIdx.x; e < 32768; e += 256) wl[e] = w2b[ph * 32768 + e];
    __syncthreads();
    for (int ktl = 0; ktl < 32; ktl++) {
      int ktg = ph * 32 + ktl;
      int ic = ktg / 5, kh = ktg - ic * 5;
      B8 fb0, fb1;
      fb0.q = *(const uint4*)&wl[(ktl*32 + lrow)*32 + lk];
      fb1.q = *(const uint4*)&wl[(ktl*32 + 16 + lrow)*32 + lk];
      int base = (ic * 19 + kh) * 66 + lk;
      #pragma unroll
      for (int q = 0; q < 3; q++) {
        if (q == 2 && wid != 0) break;
        B8 af;
        const u32* p = (const u32*)&slab[base + ohl_[q] * 132 + ow_[q] * 2];
        af.u[0] = p[0]; af.u[1] = p[1]; af.u[2] = p[2]; af.u[3] = p[3];
        acc[q][0] = __builtin_amdgcn_mfma_f32_16x16x32_bf16(af.v, fb0.v, acc[q][0], 0, 0, 0);
        acc[q][1] = __builtin_amdgcn_mfma_f32_16x16x32_bf16(af.v, fb1.v, acc[q][1], 0, 0, 0);
      }
    }
  }
  #pragma unroll
  for (int q = 0; q < 3; q++) {
    if (q == 2 && wid != 0) break;
    int mt = (q == 2) ? 8 : (wid + q * 4);
    int rb = mt * 16 + (lane >> 4) * 4;
    #pragma unroll
    for (int ct = 0; ct < 2; ct++) {
      int c = ct * 16 + lrow;
      float bias = c2b[c];
      #pragma unroll
      for (int i = 0; i < 4; i++) {
        int mr = rb + i;
        if (mr < 136) {
          int ohl = mr / 17, ow = mr - ohl * 17;
          int oh = oh0 + ohl;
          if (oh < 125) {
            float v = fmaxf(acc[q][ct][i] + bias, 0.f);
            hbf[(b*125 + oh)*544 + ow*32 + c] = f2bf(v);
          }
        }
      }
    }
  }
}

// ---------------- generic bf16 MFMA GEMM: C = A(MxK) * B(NxK)^T + bias ----------------
__global__ __launch_bounds__(256) void gemm_k(const u16* A, const u16* Bw,
                                              const float* bias, float* C,
                                              int M, int N, int K)
{
  __shared__ __align__(16) u16 As[64 * 32];
  __shared__ __align__(16) u16 Bs[64 * 32];
  int m0 = blockIdx.x * 64, n0 = blockIdx.y * 64;
  int tid = threadIdx.x;
  int lane = tid & 63, wid = tid >> 6;
  int lrow = lane & 15, lk = (lane >> 4) * 8;
  int sr = tid >> 2, sc8 = (tid & 3) * 8;
  f32x4 acc[4];
  #pragma unroll
  for (int nt = 0; nt < 4; nt++)
    #pragma unroll
    for (int i = 0; i < 4; i++) acc[nt][i] = 0.f;
  int nkt = K >> 5;
  for (int kt = 0; kt < nkt; kt++) {
    __syncthreads();
    uint4 va = make_uint4(0u, 0u, 0u, 0u);
    int arow = m0 + sr;
    if (arow < M) va = *(const uint4*)&A[arow * K + kt * 32 + sc8];
    *(uint4*)&As[sr * 32 + sc8] = va;
    uint4 vb = *(const uint4*)&Bw[(n0 + sr) * K + kt * 32 + sc8];
    *(uint4*)&Bs[sr * 32 + sc8] = vb;
    __syncthreads();
    B8 af; af.q = *(const uint4*)&As[(wid * 16 + lrow) * 32 + lk];
    #pragma unroll
    for (int nt = 0; nt < 4; nt++) {
      B8 bb; bb.q = *(const uint4*)&Bs[(nt * 16 + lrow) * 32 + lk];
      acc[nt] = __builtin_amdgcn_mfma_f32_16x16x32_bf16(af.v, bb.v, acc[nt], 0, 0, 0);
    }
  }
  #pragma unroll
  for (int nt = 0; nt < 4; nt++) {
    int col = n0 + nt * 16 + lrow;
    float bv = bias[col];
    #pragma unroll
    for (int i = 0; i < 4; i++) {
      int row = m0 + wid * 16 + (lane >> 4) * 4 + i;
      if (row < M) C[row * N + col] = acc[nt][i] + bv;
    }
  }
}

// ---------------- encoder GRU scan: 32 blocks (1/batch), 384 threads ----------------
__global__ __launch_bounds__(384) void enc_k(const u32* wT2, const float* xg,
                                             const float* bhh_g, u16* ehb)
{
  extern __shared__ char smem[];
  u32* wl = (u32*)smem;                 // 24576 u32 = 98304 B
  float* h = (float*)(smem + 98304);    // 128
  float* hg = (float*)(smem + 98816);   // 384
  int b = blockIdx.x;
  int tid = threadIdx.x;
  for (int e = tid; e < 24576; e += 384) wl[e] = wT2[e];
  if (tid < 128) h[tid] = 0.f;
  float bhh = bhh_g[tid];
  __syncthreads();
  for (int t = 0; t < 125; t++) {
    float acc = bhh;
    #pragma unroll 8
    for (int k2 = 0; k2 < 64; k2++) {
      u32 p = wl[k2 * 384 + tid];
      float2 hv = *(const float2*)&h[2 * k2];
      acc += bflo(p) * hv.x + bfhi(p) * hv.y;
    }
    hg[tid] = acc;
    __syncthreads();
    if (tid < 128) {
      const float* xr = &xg[(b * 125 + t) * 384];
      float r = sigf(xr[tid] + hg[tid]);
      float z = sigf(xr[128 + tid] + hg[128 + tid]);
      float n = tanhf(xr[256 + tid] + r * hg[256 + tid]);
      float hn = (1.f - z) * n + z * h[tid];
      h[tid] = hn;
      ehb[(((b * 64) + (tid >> 1)) * 125 + t) * 2 + (tid & 1)] = f2bf(hn);
    }
    __syncthreads();
  }
}

// ---------------- decoder GRU + attention scan: 32 blocks, 384 threads ----------------
__global__ __launch_bounds__(384) void dec_k(const u32* wT2, const u32* ehbg,
                                             const float* xgd, const float* bhh_g,
                                             const float* h_init, u16* outb)
{
  extern __shared__ char smem[];
  u32* wl = (u32*)smem;                    // 98304 B
  u32* el = (u32*)(smem + 98304);          // 32000 B  [64][125] bf16-pairs
  float* hx = (float*)(smem + 130304);     // 512
  float* hgl = (float*)(smem + 130816);    // 1536
  float* sc = (float*)(smem + 132352);     // 512
  float* red = (float*)(smem + 132864);    // 64
  int b = blockIdx.x, tid = threadIdx.x;
  for (int e = tid; e < 24576; e += 384) wl[e] = wT2[e];
  for (int e = tid; e < 8000; e += 384) el[e] = ehbg[b * 8000 + e];
  if (tid < 128) hx[tid] = h_init[tid];
  float bhh = bhh_g[tid];
  __syncthreads();

  for (int step = 0; step <= 127; step++) {
    if (step > 0) {
      int t = step - 1;
      float acc = bhh;
      #pragma unroll 8
      for (int k2 = 0; k2 < 64; k2++) {
        u32 p = wl[k2 * 384 + tid];
        float2 hv = *(const float2*)&hx[2 * k2];
        acc += bflo(p) * hv.x + bfhi(p) * hv.y;
      }
      hgl[tid] = acc;
      __syncthreads();
      if (tid < 128) {
        const float* xr = &xgd[(b * 127 + t) * 384];
        float r = sigf(xr[tid] + hgl[tid]);
        float z = sigf(xr[128 + tid] + hgl[128 + tid]);
        float n = tanhf(xr[256 + tid] + r * hgl[256 + tid]);
        hx[tid] = (1.f - z) * n + z * hx[tid];
      }
      __syncthreads();
    }
    // ---- attend: scores -> softmax -> context, hx += ctx ----
    float s;
    if (tid < 125) {
      s = 0.f;
      #pragma unroll 8
      for (int k2 = 0; k2 < 64; k2++) {
        u32 p = el[k2 * 125 + tid];
        float2 hv = *(const float2*)&hx[2 * k2];
        s += bflo(p) * hv.x + bfhi(p) * hv.y;
      }
    } else s = -1e30f;
    float mx = s;
    #pragma unroll
    for (int o = 32; o > 0; o >>= 1) mx = fmaxf(mx, __shfl_xor(mx, o));
    if ((tid & 63) == 0) red[tid >> 6] = mx;
    __syncthreads();
    mx = fmaxf(fmaxf(fmaxf(red[0], red[1]), fmaxf(red[2], red[3])), fmaxf(red[4], red[5]));
    float ev = (tid < 125) ? __expf(s - mx) : 0.f;
    float sm = ev;
    #pragma unroll
    for (int o = 32; o > 0; o >>= 1) sm += __shfl_xor(sm, o);
    __syncthreads();
    if ((tid & 63) == 0) red[tid >> 6] = sm;
    __syncthreads();
    float S = (red[0] + red[1]) + (red[2] + red[3]) + (red[4] + red[5]);
    if (tid < 125) sc[tid] = ev / S;
    __syncthreads();
    if (tid < 128) {
      const u32* ej = &el[(tid >> 1) * 125];
      bool hi = tid & 1;
      float c = 0.f;
      #pragma unroll 5
      for (int tt = 0; tt < 125; tt++) {
        u32 p = ej[tt];
        float evv = hi ? bfhi(p) : bflo(p);
        c += sc[tt] * evv;
      }
      float v = hx[tid] + c;
      hx[tid] = v;
      outb[((b * 128) + step) * 128 + tid] = f2bf(v);
    }
    __syncthreads();
  }
}

// ---------------- host launch ----------------
extern "C" void kernel_launch(void* const* d_in, const int* in_sizes, int n_in,
                              void* d_out, int out_size, void* d_ws, size_t ws_size,
                              hipStream_t stream)
{
  const float* x        = (const float*)d_in[0];
  const int*   y        = (const int*)d_in[1];
  const float* conv1_w  = (const float*)d_in[2];
  const float* conv1_b  = (const float*)d_in[3];
  const float* conv2_w  = (const float*)d_in[4];
  const float* conv2_b  = (const float*)d_in[5];
  const float* rnn_w_ih = (const float*)d_in[6];
  const float* rnn_w_hh = (const float*)d_in[7];
  const float* rnn_b_ih = (const float*)d_in[8];
  const float* rnn_b_hh = (const float*)d_in[9];
  const float* emb      = (const float*)d_in[10];
  const float* dec_w_ih = (const float*)d_in[11];
  const float* dec_w_hh = (const float*)d_in[12];
  const float* dec_b_ih = (const float*)d_in[13];
  const float* dec_b_hh = (const float*)d_in[14];
  const float* fc_w     = (const float*)d_in[15];
  const float* fc_b     = (const float*)d_in[16];
  const float* h_init   = (const float*)d_in[17];
  float* logits = (float*)d_out;

  char* ws = (char*)d_ws;
  size_t off = 0;
  auto alloc = [&](size_t bytes) { char* p = ws + off; off = (off + bytes + 255) & ~(size_t)255; return p; };
  u16* in1b  = (u16*)alloc(33812480);  // conv1 out bf16 (32,32,254,65)
  u16* hbf   = (u16*)alloc(4352000);   // h bf16 (4000,544)
  float* xge = (float*)alloc(6144000); // enc xg (4000,384)
  u32* ehb   = (u32*)alloc(1024000);   // eh packed (32,64,125)
  float* xgd = (float*)alloc(6242304); // dec xg (4064,384)
  u16* adec  = (u16*)alloc(260096);    // emb gather (4064,32)
  u16* outb  = (u16*)alloc(1048576);   // decoder out bf16 (4096,128)
  u32* wT2e  = (u32*)alloc(98304);
  u32* wT2d  = (u32*)alloc(98304);
  u16* w1b   = (u16*)alloc(10240);
  u16* w2b   = (u16*)alloc(327680);
  u16* wihb  = (u16*)alloc(417792);
  u16* dwihb = (u16*)alloc(24576);
  u16* fcwb  = (u16*)alloc(1048576);

  hipFuncSetAttribute((const void*)conv2_k, hipFuncAttributeMaxDynamicSharedMemorySize, 145792);
  hipFuncSetAttribute((const void*)enc_k,   hipFuncAttributeMaxDynamicSharedMemorySize, 100352);
  hipFuncSetAttribute((const void*)dec_k,   hipFuncAttributeMaxDynamicSharedMemorySize, 132928);

  prep_k<<<4272, 256, 0, stream>>>(rnn_w_hh, dec_w_hh, conv1_w, conv2_w, rnn_w_ih,
                                   dec_w_ih, fc_w, emb, y,
                                   wT2e, wT2d, w1b, w2b, wihb, dwihb, fcwb, adec);
  conv1_k<<<512, 256, 0, stream>>>(x, w1b, conv1_b, in1b);
  conv2_k<<<512, 256, 145792, stream>>>(in1b, w2b, conv2_b, hbf);
  gemm_k<<<dim3(63, 6), 256, 0, stream>>>(hbf, wihb, rnn_b_ih, xge, 4000, 384, 544);
  gemm_k<<<dim3(64, 6), 256, 0, stream>>>(adec, dwihb, dec_b_ih, xgd, 4064, 384, 32);
  enc_k<<<32, 384, 100352, stream>>>(wT2e, xge, rnn_b_hh, (u16*)ehb);
  dec_k<<<32, 384, 132928, stream>>>(wT2d, ehb, xgd, dec_b_hh, h_init, outb);
  gemm_k<<<dim3(64, 64), 256, 0, stream>>>(outb, fcwb, fc_b, logits, 4096, 4096, 128);
}

// Round 2
// 1075.853 us; speedup vs baseline: 1.3518x; 1.3518x over previous
//
#include <hip/hip_runtime.h>
#include <stdint.h>

typedef unsigned short u16;
typedef uint32_t u32;

typedef __bf16 bf16x8 __attribute__((ext_vector_type(8)));
typedef float f32x4 __attribute__((ext_vector_type(4)));

union B8 { uint4 q; u32 u[4]; bf16x8 v; };

__device__ __forceinline__ u16 f2bf(float f) {
  u32 u = __float_as_uint(f);
  u32 r = (u + 0x7fffu + ((u >> 16) & 1u)) >> 16;
  return (u16)r;
}
__device__ __forceinline__ float bflo(u32 p) { return __uint_as_float(p << 16); }
__device__ __forceinline__ float bfhi(u32 p) { return __uint_as_float(p & 0xffff0000u); }
__device__ __forceinline__ float sigf(float x) { return 1.f / (1.f + __expf(-x)); }
__device__ __forceinline__ float tanhf_fast(float x) {
  x = fminf(fmaxf(x, -15.f), 15.f);
  float e = __expf(2.f * x);
  return (e - 1.f) / (e + 1.f);
}

// ---------------- prep: pack/convert all weights ----------------
__global__ __launch_bounds__(256) void prep_k(
    const float* rnn_w_hh, const float* dec_w_hh, const float* conv1_w,
    const float* conv2_w, const float* rnn_w_ih, const float* dec_w_ih,
    const float* fc_w, const float* emb, const int* y,
    u32* wT2e, u32* wT2d, u16* w1b, u16* w2b, u16* wihb, u16* dwihb,
    u16* fcwb, u16* adec)
{
  int e = blockIdx.x * 256 + threadIdx.x;
  const int S0 = 24576, S1 = 24576, S2 = 5120, S3 = 163840, S4 = 208896,
            S5 = 12288, S6 = 524288, S7 = 130048;
  if (e < S0) { int g = e >> 6, k2 = e & 63;   // row-major [g][64]
    wT2e[e] = (u32)f2bf(rnn_w_hh[g*128 + 2*k2]) | ((u32)f2bf(rnn_w_hh[g*128 + 2*k2 + 1]) << 16);
    return; }
  e -= S0;
  if (e < S1) { int g = e >> 6, k2 = e & 63;
    wT2d[e] = (u32)f2bf(dec_w_hh[g*128 + 2*k2]) | ((u32)f2bf(dec_w_hh[g*128 + 2*k2 + 1]) << 16);
    return; }
  e -= S1;
  if (e < S2) { int kh = e >> 10, c = (e >> 5) & 31, kw = e & 31;
    w1b[e] = f2bf(conv1_w[c*160 + kh*32 + kw]); return; }
  e -= S2;
  if (e < S3) { int kt = e >> 10, c = (e >> 5) & 31, kw = e & 31;
    int ic = kt / 5, kh = kt - ic * 5;
    w2b[e] = f2bf(conv2_w[((c*32 + ic)*5 + kh)*32 + kw]); return; }
  e -= S3;
  if (e < S4) { wihb[e] = f2bf(rnn_w_ih[e]); return; }
  e -= S4;
  if (e < S5) { dwihb[e] = f2bf(dec_w_ih[e]); return; }
  e -= S5;
  if (e < S6) { fcwb[e] = f2bf(fc_w[e]); return; }
  e -= S6;
  if (e < S7) { int m = e >> 5, k = e & 31;
    int b = m / 127, t = m - b * 127;
    adec[e] = f2bf(emb[y[b*128 + t]*32 + k]); return; }
}

// ---------------- conv1: (32,1,512,161) -> (32,32,254,65), MFMA ----------------
__global__ __launch_bounds__(256) void conv1_k(const float* x, const u16* w1b,
                                               const float* c1b, u16* in1b)
{
  __shared__ __align__(16) u16 slab[35 * 162];
  __shared__ __align__(16) u16 wl[5120];
  int b = blockIdx.x >> 4;
  int oh0 = (blockIdx.x & 15) * 16;
  int ih0 = oh0 * 2;
  for (int e = threadIdx.x; e < 35 * 161; e += 256) {
    int r = e / 161, iw = e - r * 161;
    int ih = ih0 + r;
    float v = (ih < 512) ? x[(b*512 + ih)*161 + iw] : 0.f;
    slab[r*162 + iw] = f2bf(v);
  }
  for (int e = threadIdx.x; e < 5120; e += 256) wl[e] = w1b[e];
  __syncthreads();
  int lane = threadIdx.x & 63, wid = threadIdx.x >> 6;
  int lrow = lane & 15, lk = (lane >> 4) * 8;
  B8 bw[5][2];
  #pragma unroll
  for (int kt = 0; kt < 5; kt++)
    #pragma unroll
    for (int ct = 0; ct < 2; ct++)
      bw[kt][ct].q = *(const uint4*)&wl[(kt*32 + ct*16 + lrow)*32 + lk];
  float bias0 = c1b[lrow], bias1 = c1b[16 + lrow];
  for (int mt = wid; mt < 65; mt += 4) {
    int m = mt * 16 + lrow;
    int ohl = m / 65, ow = m - ohl * 65;
    int ro = ohl * 324 + ow * 2 + lk;
    f32x4 a0, a1;
    #pragma unroll
    for (int i = 0; i < 4; i++) { a0[i] = 0.f; a1[i] = 0.f; }
    #pragma unroll
    for (int kt = 0; kt < 5; kt++) {
      B8 af;
      const u32* p = (const u32*)&slab[ro + kt * 162];
      af.u[0] = p[0]; af.u[1] = p[1]; af.u[2] = p[2]; af.u[3] = p[3];
      a0 = __builtin_amdgcn_mfma_f32_16x16x32_bf16(af.v, bw[kt][0].v, a0, 0, 0, 0);
      a1 = __builtin_amdgcn_mfma_f32_16x16x32_bf16(af.v, bw[kt][1].v, a1, 0, 0, 0);
    }
    int rb = mt * 16 + (lane >> 4) * 4;
    #pragma unroll
    for (int i = 0; i < 4; i++) {
      int mr = rb + i;
      int ohl2 = mr / 65, ow2 = mr - ohl2 * 65;
      int oh = oh0 + ohl2;
      if (oh < 254) {
        float v0 = fmaxf(a0[i] + bias0, 0.f);
        float v1 = fmaxf(a1[i] + bias1, 0.f);
        in1b[((b*32 + lrow)*254 + oh)*65 + ow2] = f2bf(v0);
        in1b[((b*32 + 16 + lrow)*254 + oh)*65 + ow2] = f2bf(v1);
      }
    }
  }
}

// ---------------- conv2: (32,32,254,65) -> h (32,125,544) bf16, MFMA ----------------
__global__ __launch_bounds__(256) void conv2_k(const u16* in1b, const u16* w2b,
                                               const float* c2b, u16* hbf)
{
  extern __shared__ char smem[];
  u16* slab = (u16*)smem;              // [32][19][66]  = 80256 B
  u16* wl = (u16*)(smem + 80256);      // [32][32][32]  = 65536 B
  int b = blockIdx.x >> 4;
  int oh0 = (blockIdx.x & 15) * 8;
  int ih0 = oh0 * 2;
  for (int e = threadIdx.x; e < 32 * 19 * 65; e += 256) {
    int ic = e / (19 * 65);
    int rem = e - ic * (19 * 65);
    int r = rem / 65, iw = rem - r * 65;
    int ih = ih0 + r;
    u16 v = (ih < 254) ? in1b[((b*32 + ic)*254 + ih)*65 + iw] : (u16)0;
    slab[(ic*19 + r)*66 + iw] = v;
  }
  int lane = threadIdx.x & 63, wid = threadIdx.x >> 6;
  int lrow = lane & 15, lk = (lane >> 4) * 8;
  int ohl_[3], ow_[3];
  #pragma unroll
  for (int q = 0; q < 3; q++) {
    int mt = (q == 2) ? 8 : (wid + q * 4);
    int m = mt * 16 + lrow;
    if (m > 135) m = 0;
    ohl_[q] = m / 17; ow_[q] = m - ohl_[q] * 17;
  }
  f32x4 acc[3][2];
  #pragma unroll
  for (int q = 0; q < 3; q++)
    #pragma unroll
    for (int ct = 0; ct < 2; ct++)
      #pragma unroll
      for (int i = 0; i < 4; i++) acc[q][ct][i] = 0.f;

  for (int ph = 0; ph < 5; ph++) {
    __syncthreads();
    for (int e = threadIdx.x; e < 32768; e += 256) wl[e] = w2b[ph * 32768 + e];
    __syncthreads();
    for (int ktl = 0; ktl < 32; ktl++) {
      int ktg = ph * 32 + ktl;
      int ic = ktg / 5, kh = ktg - ic * 5;
      B8 fb0, fb1;
      fb0.q = *(const uint4*)&wl[(ktl*32 + lrow)*32 + lk];
      fb1.q = *(const uint4*)&wl[(ktl*32 + 16 + lrow)*32 + lk];
      int base = (ic * 19 + kh) * 66 + lk;
      #pragma unroll
      for (int q = 0; q < 3; q++) {
        if (q == 2 && wid != 0) break;
        B8 af;
        const u32* p = (const u32*)&slab[base + ohl_[q] * 132 + ow_[q] * 2];
        af.u[0] = p[0]; af.u[1] = p[1]; af.u[2] = p[2]; af.u[3] = p[3];
        acc[q][0] = __builtin_amdgcn_mfma_f32_16x16x32_bf16(af.v, fb0.v, acc[q][0], 0, 0, 0);
        acc[q][1] = __builtin_amdgcn_mfma_f32_16x16x32_bf16(af.v, fb1.v, acc[q][1], 0, 0, 0);
      }
    }
  }
  #pragma unroll
  for (int q = 0; q < 3; q++) {
    if (q == 2 && wid != 0) break;
    int mt = (q == 2) ? 8 : (wid + q * 4);
    int rb = mt * 16 + (lane >> 4) * 4;
    #pragma unroll
    for (int ct = 0; ct < 2; ct++) {
      int c = ct * 16 + lrow;
      float bias = c2b[c];
      #pragma unroll
      for (int i = 0; i < 4; i++) {
        int mr = rb + i;
        if (mr < 136) {
          int ohl = mr / 17, ow = mr - ohl * 17;
          int oh = oh0 + ohl;
          if (oh < 125) {
            float v = fmaxf(acc[q][ct][i] + bias, 0.f);
            hbf[(b*125 + oh)*544 + ow*32 + c] = f2bf(v);
          }
        }
      }
    }
  }
}

// ---------------- generic bf16 MFMA GEMM: C = A(MxK) * B(NxK)^T + bias ----------------
__global__ __launch_bounds__(256) void gemm_k(const u16* A, const u16* Bw,
                                              const float* bias, float* C,
                                              int M, int N, int K)
{
  __shared__ __align__(16) u16 As[64 * 32];
  __shared__ __align__(16) u16 Bs[64 * 32];
  int m0 = blockIdx.x * 64, n0 = blockIdx.y * 64;
  int tid = threadIdx.x;
  int lane = tid & 63, wid = tid >> 6;
  int lrow = lane & 15, lk = (lane >> 4) * 8;
  int sr = tid >> 2, sc8 = (tid & 3) * 8;
  f32x4 acc[4];
  #pragma unroll
  for (int nt = 0; nt < 4; nt++)
    #pragma unroll
    for (int i = 0; i < 4; i++) acc[nt][i] = 0.f;
  int nkt = K >> 5;
  for (int kt = 0; kt < nkt; kt++) {
    __syncthreads();
    uint4 va = make_uint4(0u, 0u, 0u, 0u);
    int arow = m0 + sr;
    if (arow < M) va = *(const uint4*)&A[arow * K + kt * 32 + sc8];
    *(uint4*)&As[sr * 32 + sc8] = va;
    uint4 vb = *(const uint4*)&Bw[(n0 + sr) * K + kt * 32 + sc8];
    *(uint4*)&Bs[sr * 32 + sc8] = vb;
    __syncthreads();
    B8 af; af.q = *(const uint4*)&As[(wid * 16 + lrow) * 32 + lk];
    #pragma unroll
    for (int nt = 0; nt < 4; nt++) {
      B8 bb; bb.q = *(const uint4*)&Bs[(nt * 16 + lrow) * 32 + lk];
      acc[nt] = __builtin_amdgcn_mfma_f32_16x16x32_bf16(af.v, bb.v, acc[nt], 0, 0, 0);
    }
  }
  #pragma unroll
  for (int nt = 0; nt < 4; nt++) {
    int col = n0 + nt * 16 + lrow;
    float bv = bias[col];
    #pragma unroll
    for (int i = 0; i < 4; i++) {
      int row = m0 + wid * 16 + (lane >> 4) * 4 + i;
      if (row < M) C[row * N + col] = acc[nt][i] + bv;
    }
  }
}

// ---------------- encoder GRU scan: 32 blocks (1/batch), 384 threads ----------------
// W_hh rows live in registers (thread g holds gate-row g, 64 packed u32).
__global__ __launch_bounds__(384, 2) void enc_k(const u32* wT2, const float* xg,
                                                const float* bhh_g, u16* ehb)
{
  __shared__ __align__(16) float h[128];
  __shared__ float hg[384];
  int b = blockIdx.x, tid = threadIdx.x;
  u32 wreg[64];
  {
    const uint4* wr = (const uint4*)(wT2 + tid * 64);
    #pragma unroll
    for (int i = 0; i < 16; i++) {
      uint4 q = wr[i];
      wreg[4*i+0] = q.x; wreg[4*i+1] = q.y; wreg[4*i+2] = q.z; wreg[4*i+3] = q.w;
    }
  }
  if (tid < 128) h[tid] = 0.f;
  float bhh = bhh_g[tid];
  float xr0 = 0.f, xr1 = 0.f, xr2 = 0.f;
  if (tid < 128) {
    const float* xp = &xg[(b * 125 + 0) * 384];
    xr0 = xp[tid]; xr1 = xp[128 + tid]; xr2 = xp[256 + tid];
  }
  __syncthreads();
  for (int t = 0; t < 125; t++) {
    float a0 = 0.f, a1 = 0.f, a2 = 0.f, a3 = 0.f;
    #pragma unroll
    for (int k4 = 0; k4 < 32; k4++) {
      float4 hv = *(const float4*)&h[4 * k4];
      u32 p0 = wreg[2*k4], p1 = wreg[2*k4 + 1];
      a0 += bflo(p0) * hv.x; a1 += bfhi(p0) * hv.y;
      a2 += bflo(p1) * hv.z; a3 += bfhi(p1) * hv.w;
    }
    hg[tid] = bhh + ((a0 + a1) + (a2 + a3));
    __syncthreads();
    if (tid < 128) {
      float r = sigf(xr0 + hg[tid]);
      float z = sigf(xr1 + hg[128 + tid]);
      float n = tanhf_fast(xr2 + r * hg[256 + tid]);
      float hn = (1.f - z) * n + z * h[tid];
      h[tid] = hn;
      ehb[(((b * 64) + (tid >> 1)) * 125 + t) * 2 + (tid & 1)] = f2bf(hn);
      if (t + 1 < 125) {
        const float* xp = &xg[(b * 125 + t + 1) * 384];
        xr0 = xp[tid]; xr1 = xp[128 + tid]; xr2 = xp[256 + tid];
      }
    }
    __syncthreads();
  }
}

// ---------------- decoder GRU + attention scan: 32 blocks, 384 threads ----------------
__global__ __launch_bounds__(384, 2) void dec_k(const u32* wT2, const u32* ehbg,
                                                const float* xgd, const float* bhh_g,
                                                const float* h_init, u16* outb)
{
  __shared__ __align__(16) u32 el[8000];      // [64][125] bf16-pairs
  __shared__ __align__(16) float hx[128];
  __shared__ float hg[384];
  __shared__ float ps[384];                   // [3][128] score partials
  __shared__ float sc[128];                   // exp(s - m_wave)
  __shared__ float cp[256];                   // [2][128] context partials
  __shared__ float red[8];
  int b = blockIdx.x, tid = threadIdx.x;
  u32 wreg[64];
  {
    const uint4* wr = (const uint4*)(wT2 + tid * 64);
    #pragma unroll
    for (int i = 0; i < 16; i++) {
      uint4 q = wr[i];
      wreg[4*i+0] = q.x; wreg[4*i+1] = q.y; wreg[4*i+2] = q.z; wreg[4*i+3] = q.w;
    }
  }
  for (int e = tid; e < 8000; e += 384) el[e] = ehbg[b * 8000 + e];
  if (tid < 128) hx[tid] = h_init[tid];
  float bhh = bhh_g[tid];
  int sj = tid >> 7, st = tid & 127;          // scores: K-split 3-way
  int cj = tid >> 7, ck = tid & 127;          // context: T-split 2-way (cj<2)
  float xr0 = 0.f, xr1 = 0.f, xr2 = 0.f;
  if (tid < 128) {
    const float* xp = &xgd[(b * 127 + 0) * 384];
    xr0 = xp[tid]; xr1 = xp[128 + tid]; xr2 = xp[256 + tid];
  }
  __syncthreads();

  for (int step = 0; step <= 127; step++) {
    if (step > 0) {
      // ---- GRU matvec from registers ----
      float a0 = 0.f, a1 = 0.f, a2 = 0.f, a3 = 0.f;
      #pragma unroll
      for (int k4 = 0; k4 < 32; k4++) {
        float4 hv = *(const float4*)&hx[4 * k4];
        u32 p0 = wreg[2*k4], p1 = wreg[2*k4 + 1];
        a0 += bflo(p0) * hv.x; a1 += bfhi(p0) * hv.y;
        a2 += bflo(p1) * hv.z; a3 += bfhi(p1) * hv.w;
      }
      hg[tid] = bhh + ((a0 + a1) + (a2 + a3));
      __syncthreads();                         // B1
      if (tid < 128) {
        float r = sigf(xr0 + hg[tid]);
        float z = sigf(xr1 + hg[128 + tid]);
        float n = tanhf_fast(xr2 + r * hg[256 + tid]);
        hx[tid] = (1.f - z) * n + z * hx[tid];
        if (step < 127) {
          const float* xp = &xgd[(b * 127 + step) * 384];
          xr0 = xp[tid]; xr1 = xp[128 + tid]; xr2 = xp[256 + tid];
        }
      }
      __syncthreads();                         // B2
    }
    // ---- scores partials: s[t] = eh[t]·hx, K split 3 ways ----
    {
      float s0 = 0.f, s1 = 0.f;
      if (st < 125) {
        int k2lo = sj * 22, k2hi = (sj == 2) ? 64 : (sj * 22 + 22);
        for (int k2 = k2lo; k2 < k2hi; k2 += 2) {
          u32 pa = el[k2 * 125 + st];
          u32 pb = el[(k2 + 1) * 125 + st];
          float2 ha = *(const float2*)&hx[2 * k2];
          float2 hb = *(const float2*)&hx[2 * k2 + 2];
          s0 += bflo(pa) * ha.x + bfhi(pa) * ha.y;
          s1 += bflo(pb) * hb.x + bfhi(pb) * hb.y;
        }
      }
      ps[tid] = s0 + s1;
    }
    __syncthreads();                           // B3
    // ---- softmax: per-wave max/sum, combined via scale factors ----
    if (tid < 128) {
      float s = (tid < 125) ? ps[tid] + ps[128 + tid] + ps[256 + tid] : -1e30f;
      float mw = s;
      #pragma unroll
      for (int o = 32; o > 0; o >>= 1) mw = fmaxf(mw, __shfl_xor(mw, o));
      float ev = (tid < 125) ? __expf(s - mw) : 0.f;
      float sw = ev;
      #pragma unroll
      for (int o = 32; o > 0; o >>= 1) sw += __shfl_xor(sw, o);
      sc[tid] = ev;
      if ((tid & 63) == 0) { red[(tid >> 6) * 2] = mw; red[(tid >> 6) * 2 + 1] = sw; }
    }
    __syncthreads();                           // B4
    float m0 = red[0], S0 = red[1], m1 = red[2], S1 = red[3];
    float M = fmaxf(m0, m1);
    float f0 = __expf(m0 - M), f1 = __expf(m1 - M);
    float inv = 1.f / (S0 * f0 + S1 * f1);
    // ---- context partials: T split 2 ways (t<64 | t>=64) ----
    if (cj < 2) {
      int k2 = ck >> 1; bool hi = ck & 1;
      const u32* ep = &el[k2 * 125];
      int tlo = cj ? 64 : 0, thi = cj ? 125 : 64;
      float ca = 0.f, cb = 0.f;
      int t = tlo;
      for (; t + 1 < thi; t += 2) {
        u32 p0 = ep[t], p1 = ep[t + 1];
        ca += sc[t]     * (hi ? bfhi(p0) : bflo(p0));
        cb += sc[t + 1] * (hi ? bfhi(p1) : bflo(p1));
      }
      if (t < thi) ca += sc[t] * (hi ? bfhi(ep[t]) : bflo(ep[t]));
      cp[cj * 128 + ck] = (ca + cb) * (cj ? f1 : f0);
    }
    __syncthreads();                           // B5
    if (tid < 128) {
      float v = hx[tid] + (cp[tid] + cp[128 + tid]) * inv;
      hx[tid] = v;
      outb[((b * 128) + step) * 128 + tid] = f2bf(v);
    }
    __syncthreads();                           // B6
  }
}

// ---------------- host launch ----------------
extern "C" void kernel_launch(void* const* d_in, const int* in_sizes, int n_in,
                              void* d_out, int out_size, void* d_ws, size_t ws_size,
                              hipStream_t stream)
{
  const float* x        = (const float*)d_in[0];
  const int*   y        = (const int*)d_in[1];
  const float* conv1_w  = (const float*)d_in[2];
  const float* conv1_b  = (const float*)d_in[3];
  const float* conv2_w  = (const float*)d_in[4];
  const float* conv2_b  = (const float*)d_in[5];
  const float* rnn_w_ih = (const float*)d_in[6];
  const float* rnn_w_hh = (const float*)d_in[7];
  const float* rnn_b_ih = (const float*)d_in[8];
  const float* rnn_b_hh = (const float*)d_in[9];
  const float* emb      = (const float*)d_in[10];
  const float* dec_w_ih = (const float*)d_in[11];
  const float* dec_w_hh = (const float*)d_in[12];
  const float* dec_b_ih = (const float*)d_in[13];
  const float* dec_b_hh = (const float*)d_in[14];
  const float* fc_w     = (const float*)d_in[15];
  const float* fc_b     = (const float*)d_in[16];
  const float* h_init   = (const float*)d_in[17];
  float* logits = (float*)d_out;

  char* ws = (char*)d_ws;
  size_t off = 0;
  auto alloc = [&](size_t bytes) { char* p = ws + off; off = (off + bytes + 255) & ~(size_t)255; return p; };
  u16* in1b  = (u16*)alloc(33812480);  // conv1 out bf16 (32,32,254,65)
  u16* hbf   = (u16*)alloc(4352000);   // h bf16 (4000,544)
  float* xge = (float*)alloc(6144000); // enc xg (4000,384)
  u32* ehb   = (u32*)alloc(1024000);   // eh packed (32,64,125)
  float* xgd = (float*)alloc(6242304); // dec xg (4064,384)
  u16* adec  = (u16*)alloc(260096);    // emb gather (4064,32)
  u16* outb  = (u16*)alloc(1048576);   // decoder out bf16 (4096,128)
  u32* wT2e  = (u32*)alloc(98304);
  u32* wT2d  = (u32*)alloc(98304);
  u16* w1b   = (u16*)alloc(10240);
  u16* w2b   = (u16*)alloc(327680);
  u16* wihb  = (u16*)alloc(417792);
  u16* dwihb = (u16*)alloc(24576);
  u16* fcwb  = (u16*)alloc(1048576);

  hipFuncSetAttribute((const void*)conv2_k, hipFuncAttributeMaxDynamicSharedMemorySize, 145792);

  prep_k<<<4272, 256, 0, stream>>>(rnn_w_hh, dec_w_hh, conv1_w, conv2_w, rnn_w_ih,
                                   dec_w_ih, fc_w, emb, y,
                                   wT2e, wT2d, w1b, w2b, wihb, dwihb, fcwb, adec);
  conv1_k<<<512, 256, 0, stream>>>(x, w1b, conv1_b, in1b);
  conv2_k<<<512, 256, 145792, stream>>>(in1b, w2b, conv2_b, hbf);
  gemm_k<<<dim3(63, 6), 256, 0, stream>>>(hbf, wihb, rnn_b_ih, xge, 4000, 384, 544);
  gemm_k<<<dim3(64, 6), 256, 0, stream>>>(adec, dwihb, dec_b_ih, xgd, 4064, 384, 32);
  enc_k<<<32, 384, 0, stream>>>(wT2e, xge, rnn_b_hh, (u16*)ehb);
  dec_k<<<32, 384, 0, stream>>>(wT2d, ehb, xgd, dec_b_hh, h_init, outb);
  gemm_k<<<dim3(64, 64), 256, 0, stream>>>(outb, fcwb, fc_b, logits, 4096, 4096, 128);
}

// Round 3
// 804.545 us; speedup vs baseline: 1.8077x; 1.3372x over previous
//
#include <hip/hip_runtime.h>
#include <stdint.h>

typedef unsigned short u16;
typedef uint32_t u32;

typedef __bf16 bf16x8 __attribute__((ext_vector_type(8)));
typedef float f32x4 __attribute__((ext_vector_type(4)));
typedef _Float16 h2v __attribute__((ext_vector_type(2)));

union B8 { uint4 q; u32 u[4]; bf16x8 v; };

__device__ __forceinline__ u16 f2bf(float f) {
  u32 u = __float_as_uint(f);
  u32 r = (u + 0x7fffu + ((u >> 16) & 1u)) >> 16;
  return (u16)r;
}
__device__ __forceinline__ u16 f2h(float f) {
  union { _Float16 h; u16 u; } v; v.h = (_Float16)f; return v.u;
}
__device__ __forceinline__ float dot2h(u32 a, u32 b, float c) {
  union U { u32 u; h2v v; } A, B; A.u = a; B.u = b;
  return __builtin_amdgcn_fdot2(A.v, B.v, c, false);
}
__device__ __forceinline__ float sigf(float x) { return 1.f / (1.f + __expf(-x)); }
__device__ __forceinline__ float tanhf_fast(float x) {
  x = fminf(fmaxf(x, -15.f), 15.f);
  float e = __expf(2.f * x);
  return (e - 1.f) / (e + 1.f);
}

// ---------------- prep: pack/convert all weights ----------------
__global__ __launch_bounds__(256) void prep_k(
    const float* rnn_w_hh, const float* dec_w_hh, const float* conv1_w,
    const float* conv2_w, const float* rnn_w_ih, const float* dec_w_ih,
    const float* fc_w, const float* emb, const int* y,
    u32* wT2e, u32* wT2d, u16* w1b, u16* w2b, u16* wihb, u16* dwihb,
    u16* fcwb, u16* adec)
{
  int e = blockIdx.x * 256 + threadIdx.x;
  const int S0 = 24576, S1 = 24576, S2 = 5120, S3 = 163840, S4 = 208896,
            S5 = 12288, S6 = 524288, S7 = 130048;
  if (e < S0) { int g = e >> 6, k2 = e & 63;   // row-major [g][64], f16 pairs
    wT2e[e] = (u32)f2h(rnn_w_hh[g*128 + 2*k2]) | ((u32)f2h(rnn_w_hh[g*128 + 2*k2 + 1]) << 16);
    return; }
  e -= S0;
  if (e < S1) { int g = e >> 6, k2 = e & 63;
    wT2d[e] = (u32)f2h(dec_w_hh[g*128 + 2*k2]) | ((u32)f2h(dec_w_hh[g*128 + 2*k2 + 1]) << 16);
    return; }
  e -= S1;
  if (e < S2) { int kh = e >> 10, c = (e >> 5) & 31, kw = e & 31;
    w1b[e] = f2bf(conv1_w[c*160 + kh*32 + kw]); return; }
  e -= S2;
  if (e < S3) { int kt = e >> 10, c = (e >> 5) & 31, kw = e & 31;
    int ic = kt / 5, kh = kt - ic * 5;
    w2b[e] = f2bf(conv2_w[((c*32 + ic)*5 + kh)*32 + kw]); return; }
  e -= S3;
  if (e < S4) { wihb[e] = f2bf(rnn_w_ih[e]); return; }
  e -= S4;
  if (e < S5) { dwihb[e] = f2bf(dec_w_ih[e]); return; }
  e -= S5;
  if (e < S6) { fcwb[e] = f2bf(fc_w[e]); return; }
  e -= S6;
  if (e < S7) { int m = e >> 5, k = e & 31;
    int b = m / 127, t = m - b * 127;
    adec[e] = f2bf(emb[y[b*128 + t]*32 + k]); return; }
}

// ---------------- conv1: (32,1,512,161) -> (32,32,254,65), MFMA ----------------
__global__ __launch_bounds__(256) void conv1_k(const float* x, const u16* w1b,
                                               const float* c1b, u16* in1b)
{
  __shared__ __align__(16) u16 slab[35 * 162];
  __shared__ __align__(16) u16 wl[5120];
  int b = blockIdx.x >> 4;
  int oh0 = (blockIdx.x & 15) * 16;
  int ih0 = oh0 * 2;
  for (int e = threadIdx.x; e < 35 * 161; e += 256) {
    int r = e / 161, iw = e - r * 161;
    int ih = ih0 + r;
    float v = (ih < 512) ? x[(b*512 + ih)*161 + iw] : 0.f;
    slab[r*162 + iw] = f2bf(v);
  }
  for (int e = threadIdx.x; e < 5120; e += 256) wl[e] = w1b[e];
  __syncthreads();
  int lane = threadIdx.x & 63, wid = threadIdx.x >> 6;
  int lrow = lane & 15, lk = (lane >> 4) * 8;
  B8 bw[5][2];
  #pragma unroll
  for (int kt = 0; kt < 5; kt++)
    #pragma unroll
    for (int ct = 0; ct < 2; ct++)
      bw[kt][ct].q = *(const uint4*)&wl[(kt*32 + ct*16 + lrow)*32 + lk];
  float bias0 = c1b[lrow], bias1 = c1b[16 + lrow];
  for (int mt = wid; mt < 65; mt += 4) {
    int m = mt * 16 + lrow;
    int ohl = m / 65, ow = m - ohl * 65;
    int ro = ohl * 324 + ow * 2 + lk;
    f32x4 a0, a1;
    #pragma unroll
    for (int i = 0; i < 4; i++) { a0[i] = 0.f; a1[i] = 0.f; }
    #pragma unroll
    for (int kt = 0; kt < 5; kt++) {
      B8 af;
      const u32* p = (const u32*)&slab[ro + kt * 162];
      af.u[0] = p[0]; af.u[1] = p[1]; af.u[2] = p[2]; af.u[3] = p[3];
      a0 = __builtin_amdgcn_mfma_f32_16x16x32_bf16(af.v, bw[kt][0].v, a0, 0, 0, 0);
      a1 = __builtin_amdgcn_mfma_f32_16x16x32_bf16(af.v, bw[kt][1].v, a1, 0, 0, 0);
    }
    int rb = mt * 16 + (lane >> 4) * 4;
    #pragma unroll
    for (int i = 0; i < 4; i++) {
      int mr = rb + i;
      int ohl2 = mr / 65, ow2 = mr - ohl2 * 65;
      int oh = oh0 + ohl2;
      if (oh < 254) {
        float v0 = fmaxf(a0[i] + bias0, 0.f);
        float v1 = fmaxf(a1[i] + bias1, 0.f);
        in1b[((b*32 + lrow)*254 + oh)*65 + ow2] = f2bf(v0);
        in1b[((b*32 + 16 + lrow)*254 + oh)*65 + ow2] = f2bf(v1);
      }
    }
  }
}

// ---------------- conv2: (32,32,254,65) -> h (32,125,544) bf16, MFMA ----------------
__global__ __launch_bounds__(256) void conv2_k(const u16* in1b, const u16* w2b,
                                               const float* c2b, u16* hbf)
{
  extern __shared__ char smem[];
  u16* slab = (u16*)smem;              // [32][19][66]  = 80256 B
  u16* wl = (u16*)(smem + 80256);      // [32][32][32]  = 65536 B
  int b = blockIdx.x >> 4;
  int oh0 = (blockIdx.x & 15) * 8;
  int ih0 = oh0 * 2;
  for (int e = threadIdx.x; e < 32 * 19 * 65; e += 256) {
    int ic = e / (19 * 65);
    int rem = e - ic * (19 * 65);
    int r = rem / 65, iw = rem - r * 65;
    int ih = ih0 + r;
    u16 v = (ih < 254) ? in1b[((b*32 + ic)*254 + ih)*65 + iw] : (u16)0;
    slab[(ic*19 + r)*66 + iw] = v;
  }
  int lane = threadIdx.x & 63, wid = threadIdx.x >> 6;
  int lrow = lane & 15, lk = (lane >> 4) * 8;
  int ohl_[3], ow_[3];
  #pragma unroll
  for (int q = 0; q < 3; q++) {
    int mt = (q == 2) ? 8 : (wid + q * 4);
    int m = mt * 16 + lrow;
    if (m > 135) m = 0;
    ohl_[q] = m / 17; ow_[q] = m - ohl_[q] * 17;
  }
  f32x4 acc[3][2];
  #pragma unroll
  for (int q = 0; q < 3; q++)
    #pragma unroll
    for (int ct = 0; ct < 2; ct++)
      #pragma unroll
      for (int i = 0; i < 4; i++) acc[q][ct][i] = 0.f;

  for (int ph = 0; ph < 5; ph++) {
    __syncthreads();
    for (int e = threadIdx.x; e < 32768; e += 256) wl[e] = w2b[ph * 32768 + e];
    __syncthreads();
    for (int ktl = 0; ktl < 32; ktl++) {
      int ktg = ph * 32 + ktl;
      int ic = ktg / 5, kh = ktg - ic * 5;
      B8 fb0, fb1;
      fb0.q = *(const uint4*)&wl[(ktl*32 + lrow)*32 + lk];
      fb1.q = *(const uint4*)&wl[(ktl*32 + 16 + lrow)*32 + lk];
      int base = (ic * 19 + kh) * 66 + lk;
      #pragma unroll
      for (int q = 0; q < 3; q++) {
        if (q == 2 && wid != 0) break;
        B8 af;
        const u32* p = (const u32*)&slab[base + ohl_[q] * 132 + ow_[q] * 2];
        af.u[0] = p[0]; af.u[1] = p[1]; af.u[2] = p[2]; af.u[3] = p[3];
        acc[q][0] = __builtin_amdgcn_mfma_f32_16x16x32_bf16(af.v, fb0.v, acc[q][0], 0, 0, 0);
        acc[q][1] = __builtin_amdgcn_mfma_f32_16x16x32_bf16(af.v, fb1.v, acc[q][1], 0, 0, 0);
      }
    }
  }
  #pragma unroll
  for (int q = 0; q < 3; q++) {
    if (q == 2 && wid != 0) break;
    int mt = (q == 2) ? 8 : (wid + q * 4);
    int rb = mt * 16 + (lane >> 4) * 4;
    #pragma unroll
    for (int ct = 0; ct < 2; ct++) {
      int c = ct * 16 + lrow;
      float bias = c2b[c];
      #pragma unroll
      for (int i = 0; i < 4; i++) {
        int mr = rb + i;
        if (mr < 136) {
          int ohl = mr / 17, ow = mr - ohl * 17;
          int oh = oh0 + ohl;
          if (oh < 125) {
            float v = fmaxf(acc[q][ct][i] + bias, 0.f);
            hbf[(b*125 + oh)*544 + ow*32 + c] = f2bf(v);
          }
        }
      }
    }
  }
}

// ---------------- generic bf16 MFMA GEMM: C = A(MxK) * B(NxK)^T + bias ----------------
__global__ __launch_bounds__(256) void gemm_k(const u16* A, const u16* Bw,
                                              const float* bias, float* C,
                                              int M, int N, int K)
{
  __shared__ __align__(16) u16 As[64 * 32];
  __shared__ __align__(16) u16 Bs[64 * 32];
  int m0 = blockIdx.x * 64, n0 = blockIdx.y * 64;
  int tid = threadIdx.x;
  int lane = tid & 63, wid = tid >> 6;
  int lrow = lane & 15, lk = (lane >> 4) * 8;
  int sr = tid >> 2, sc8 = (tid & 3) * 8;
  f32x4 acc[4];
  #pragma unroll
  for (int nt = 0; nt < 4; nt++)
    #pragma unroll
    for (int i = 0; i < 4; i++) acc[nt][i] = 0.f;
  int nkt = K >> 5;
  for (int kt = 0; kt < nkt; kt++) {
    __syncthreads();
    uint4 va = make_uint4(0u, 0u, 0u, 0u);
    int arow = m0 + sr;
    if (arow < M) va = *(const uint4*)&A[arow * K + kt * 32 + sc8];
    *(uint4*)&As[sr * 32 + sc8] = va;
    uint4 vb = *(const uint4*)&Bw[(n0 + sr) * K + kt * 32 + sc8];
    *(uint4*)&Bs[sr * 32 + sc8] = vb;
    __syncthreads();
    B8 af; af.q = *(const uint4*)&As[(wid * 16 + lrow) * 32 + lk];
    #pragma unroll
    for (int nt = 0; nt < 4; nt++) {
      B8 bb; bb.q = *(const uint4*)&Bs[(nt * 16 + lrow) * 32 + lk];
      acc[nt] = __builtin_amdgcn_mfma_f32_16x16x32_bf16(af.v, bb.v, acc[nt], 0, 0, 0);
    }
  }
  #pragma unroll
  for (int nt = 0; nt < 4; nt++) {
    int col = n0 + nt * 16 + lrow;
    float bv = bias[col];
    #pragma unroll
    for (int i = 0; i < 4; i++) {
      int row = m0 + wid * 16 + (lane >> 4) * 4 + i;
      if (row < M) C[row * N + col] = acc[nt][i] + bv;
    }
  }
}

// ---------------- encoder GRU scan: 32 blocks, 128 threads (thread i = unit i) ----------------
__global__ __launch_bounds__(128, 1) void enc_k(const u32* wT2, const float* xg,
                                                const float* bhh_g, u16* ehk, u16* eht)
{
  __shared__ __align__(16) u32 hp[2][64];   // f16-pair h, double-buffered
  int b = blockIdx.x, tid = threadIdx.x;
  u32 w0[64], w1[64], w2[64];
  {
    const uint4* p0 = (const uint4*)(wT2 + (size_t)tid * 64);
    const uint4* p1 = (const uint4*)(wT2 + (size_t)(128 + tid) * 64);
    const uint4* p2 = (const uint4*)(wT2 + (size_t)(256 + tid) * 64);
    #pragma unroll
    for (int j = 0; j < 16; j++) {
      uint4 q0 = p0[j]; w0[4*j] = q0.x; w0[4*j+1] = q0.y; w0[4*j+2] = q0.z; w0[4*j+3] = q0.w;
      uint4 q1 = p1[j]; w1[4*j] = q1.x; w1[4*j+1] = q1.y; w1[4*j+2] = q1.z; w1[4*j+3] = q1.w;
      uint4 q2 = p2[j]; w2[4*j] = q2.x; w2[4*j+1] = q2.y; w2[4*j+2] = q2.z; w2[4*j+3] = q2.w;
    }
  }
  float b0 = bhh_g[tid], b1 = bhh_g[128 + tid], b2 = bhh_g[256 + tid];
  float h_reg = 0.f;
  ((u16*)&hp[0][0])[tid] = 0;
  const float* xp = &xg[(size_t)b * 125 * 384];
  float xr0 = xp[tid], xr1 = xp[128 + tid], xr2 = xp[256 + tid];
  __syncthreads();
  for (int t = 0; t < 125; t++) {
    const u32* hb = &hp[t & 1][0];
    uint4 hw[16];
    #pragma unroll
    for (int j = 0; j < 16; j++) hw[j] = *(const uint4*)&hb[4*j];
    float r0 = b0, r1 = 0.f, z0 = b1, z1 = 0.f, n0 = b2, n1 = 0.f;
    #pragma unroll
    for (int j = 0; j < 16; j++) {
      r0 = dot2h(w0[4*j+0], hw[j].x, r0); r1 = dot2h(w0[4*j+1], hw[j].y, r1);
      r0 = dot2h(w0[4*j+2], hw[j].z, r0); r1 = dot2h(w0[4*j+3], hw[j].w, r1);
      z0 = dot2h(w1[4*j+0], hw[j].x, z0); z1 = dot2h(w1[4*j+1], hw[j].y, z1);
      z0 = dot2h(w1[4*j+2], hw[j].z, z0); z1 = dot2h(w1[4*j+3], hw[j].w, z1);
      n0 = dot2h(w2[4*j+0], hw[j].x, n0); n1 = dot2h(w2[4*j+1], hw[j].y, n1);
      n0 = dot2h(w2[4*j+2], hw[j].z, n0); n1 = dot2h(w2[4*j+3], hw[j].w, n1);
    }
    float r = sigf(xr0 + r0 + r1);
    float z = sigf(xr1 + z0 + z1);
    float n = tanhf_fast(xr2 + r * (n0 + n1));
    h_reg = (1.f - z) * n + z * h_reg;
    u16 hv = f2h(h_reg);
    ((u16*)&hp[(t & 1) ^ 1][0])[tid] = hv;
    ehk[((size_t)(b*64 + (tid >> 1)) * 125 + t) * 2 + (tid & 1)] = hv;
    eht[((size_t)(b*128 + tid)) * 128 + t] = hv;
    if (t + 1 < 125) {
      const float* xq = &xg[((size_t)b * 125 + t + 1) * 384];
      xr0 = xq[tid]; xr1 = xq[128 + tid]; xr2 = xq[256 + tid];
    }
    __syncthreads();
  }
  // zero pads t=125..127 in eht
  size_t rbase = ((size_t)(b*128 + tid)) * 128;
  eht[rbase + 125] = 0; eht[rbase + 126] = 0; eht[rbase + 127] = 0;
}

// ---------------- decoder GRU + attention: 32 blocks, 128 threads ----------------
__global__ __launch_bounds__(128, 1) void dec_k(const u32* wT2, const u32* ehk_g,
                                                const u32* eht_g, const float* xgd,
                                                const float* bhh_g, const float* h_init,
                                                u16* outb)
{
  extern __shared__ char sm[];
  u32* elK = (u32*)sm;                  // [64][125] f16 k-pairs (+slack)   32256 B
  u32* elT = (u32*)(sm + 32256);        // [128][66] f16 t-pairs            33792 B
  u32* hxA = (u32*)(sm + 66048);        // post-GRU hx pairs                  256 B
  u32* hxB = (u32*)(sm + 66304);        // post-attn hx pairs                 256 B
  u32* scp = (u32*)(sm + 66560);        // softmax weights f16[128]           256 B
  float* red = (float*)(sm + 66816);    // per-wave (max,sum)                  32 B
  int b = blockIdx.x, tid = threadIdx.x;
  int wv = tid >> 6;
  u32 w0[64], w1[64], w2[64];
  {
    const uint4* p0 = (const uint4*)(wT2 + (size_t)tid * 64);
    const uint4* p1 = (const uint4*)(wT2 + (size_t)(128 + tid) * 64);
    const uint4* p2 = (const uint4*)(wT2 + (size_t)(256 + tid) * 64);
    #pragma unroll
    for (int j = 0; j < 16; j++) {
      uint4 q0 = p0[j]; w0[4*j] = q0.x; w0[4*j+1] = q0.y; w0[4*j+2] = q0.z; w0[4*j+3] = q0.w;
      uint4 q1 = p1[j]; w1[4*j] = q1.x; w1[4*j+1] = q1.y; w1[4*j+2] = q1.z; w1[4*j+3] = q1.w;
      uint4 q2 = p2[j]; w2[4*j] = q2.x; w2[4*j+1] = q2.y; w2[4*j+2] = q2.z; w2[4*j+3] = q2.w;
    }
  }
  float b0 = bhh_g[tid], b1 = bhh_g[128 + tid], b2 = bhh_g[256 + tid];
  for (int e = tid; e < 8000; e += 128) elK[e] = ehk_g[(size_t)b * 8000 + e];
  for (int w = tid; w < 8192; w += 128) elT[(w >> 6) * 66 + (w & 63)] = eht_g[(size_t)b * 8192 + w];
  float hx_reg = h_init[tid];
  const float* xp = &xgd[(size_t)b * 127 * 384];
  float xr0 = xp[tid], xr1 = xp[128 + tid], xr2 = xp[256 + tid];
  __syncthreads();

  for (int step = 0; step <= 127; step++) {
    if (step > 0) {
      // ---- GRU: all 3 gates for unit tid, weights in registers ----
      uint4 hw[16];
      #pragma unroll
      for (int j = 0; j < 16; j++) hw[j] = *(const uint4*)&hxB[4*j];
      float r0 = b0, r1 = 0.f, z0 = b1, z1 = 0.f, n0 = b2, n1 = 0.f;
      #pragma unroll
      for (int j = 0; j < 16; j++) {
        r0 = dot2h(w0[4*j+0], hw[j].x, r0); r1 = dot2h(w0[4*j+1], hw[j].y, r1);
        r0 = dot2h(w0[4*j+2], hw[j].z, r0); r1 = dot2h(w0[4*j+3], hw[j].w, r1);
        z0 = dot2h(w1[4*j+0], hw[j].x, z0); z1 = dot2h(w1[4*j+1], hw[j].y, z1);
        z0 = dot2h(w1[4*j+2], hw[j].z, z0); z1 = dot2h(w1[4*j+3], hw[j].w, z1);
        n0 = dot2h(w2[4*j+0], hw[j].x, n0); n1 = dot2h(w2[4*j+1], hw[j].y, n1);
        n0 = dot2h(w2[4*j+2], hw[j].z, n0); n1 = dot2h(w2[4*j+3], hw[j].w, n1);
      }
      float r = sigf(xr0 + r0 + r1);
      float z = sigf(xr1 + z0 + z1);
      float n = tanhf_fast(xr2 + r * (n0 + n1));
      hx_reg = (1.f - z) * n + z * hx_reg;
      if (step < 127) {
        const float* xq = &xgd[((size_t)b * 127 + step) * 384];
        xr0 = xq[tid]; xr1 = xq[128 + tid]; xr2 = xq[256 + tid];
      }
    }
    ((u16*)hxA)[tid] = f2h(hx_reg);
    __syncthreads();                        // B2: hxA ready
    // ---- scores: s[t] = eh[t]·hx (f16 dot2), t = tid ----
    uint4 aw[16];
    #pragma unroll
    for (int j = 0; j < 16; j++) aw[j] = *(const uint4*)&hxA[4*j];
    float s0 = 0.f, s1 = 0.f, s2 = 0.f, s3 = 0.f;
    #pragma unroll
    for (int j = 0; j < 16; j++) {
      s0 = dot2h(elK[(4*j+0)*125 + tid], aw[j].x, s0);
      s1 = dot2h(elK[(4*j+1)*125 + tid], aw[j].y, s1);
      s2 = dot2h(elK[(4*j+2)*125 + tid], aw[j].z, s2);
      s3 = dot2h(elK[(4*j+3)*125 + tid], aw[j].w, s3);
    }
    float s = (tid < 125) ? ((s0 + s1) + (s2 + s3)) : -1e30f;
    float mw = s;
    #pragma unroll
    for (int o = 32; o > 0; o >>= 1) mw = fmaxf(mw, __shfl_xor(mw, o));
    float ev = (tid < 125) ? __expf(s - mw) : 0.f;
    float sw = ev;
    #pragma unroll
    for (int o = 32; o > 0; o >>= 1) sw += __shfl_xor(sw, o);
    ((u16*)scp)[tid] = f2h(ev);
    if ((tid & 63) == 0) { red[wv*2] = mw; red[wv*2 + 1] = sw; }
    __syncthreads();                        // B3: sc + red ready
    // ---- combine waves + context: ctx[i] = Σ_t sc[t]·eh[t][i] ----
    float m0r = red[0], S0r = red[1], m1r = red[2], S1r = red[3];
    float M = fmaxf(m0r, m1r);
    float f0 = __expf(m0r - M), f1 = __expf(m1r - M);
    float inv = 1.f / (f0 * S0r + f1 * S1r);
    uint4 scw[16];
    #pragma unroll
    for (int j = 0; j < 16; j++) scw[j] = *(const uint4*)&scp[4*j];
    const u32* row = &elT[tid * 66];
    float cA0 = 0.f, cA1 = 0.f, cB0 = 0.f, cB1 = 0.f;
    #pragma unroll
    for (int j = 0; j < 8; j++) {          // t-pairs 0..31 (t<64) -> wave0 scale
      uint2 e0 = *(const uint2*)&row[4*j];
      uint2 e1 = *(const uint2*)&row[4*j + 2];
      cA0 = dot2h(e0.x, scw[j].x, cA0); cA1 = dot2h(e0.y, scw[j].y, cA1);
      cA0 = dot2h(e1.x, scw[j].z, cA0); cA1 = dot2h(e1.y, scw[j].w, cA1);
    }
    #pragma unroll
    for (int j = 8; j < 16; j++) {         // t-pairs 32..63 (t>=64) -> wave1 scale
      uint2 e0 = *(const uint2*)&row[4*j];
      uint2 e1 = *(const uint2*)&row[4*j + 2];
      cB0 = dot2h(e0.x, scw[j].x, cB0); cB1 = dot2h(e0.y, scw[j].y, cB1);
      cB0 = dot2h(e1.x, scw[j].z, cB0); cB1 = dot2h(e1.y, scw[j].w, cB1);
    }
    hx_reg += ((cA0 + cA1) * f0 + (cB0 + cB1) * f1) * inv;
    outb[((size_t)(b * 128) + step) * 128 + tid] = f2bf(hx_reg);
    ((u16*)hxB)[tid] = f2h(hx_reg);
    __syncthreads();                        // B1: hxB ready for next matvec
  }
}

// ---------------- host launch ----------------
extern "C" void kernel_launch(void* const* d_in, const int* in_sizes, int n_in,
                              void* d_out, int out_size, void* d_ws, size_t ws_size,
                              hipStream_t stream)
{
  const float* x        = (const float*)d_in[0];
  const int*   y        = (const int*)d_in[1];
  const float* conv1_w  = (const float*)d_in[2];
  const float* conv1_b  = (const float*)d_in[3];
  const float* conv2_w  = (const float*)d_in[4];
  const float* conv2_b  = (const float*)d_in[5];
  const float* rnn_w_ih = (const float*)d_in[6];
  const float* rnn_w_hh = (const float*)d_in[7];
  const float* rnn_b_ih = (const float*)d_in[8];
  const float* rnn_b_hh = (const float*)d_in[9];
  const float* emb      = (const float*)d_in[10];
  const float* dec_w_ih = (const float*)d_in[11];
  const float* dec_w_hh = (const float*)d_in[12];
  const float* dec_b_ih = (const float*)d_in[13];
  const float* dec_b_hh = (const float*)d_in[14];
  const float* fc_w     = (const float*)d_in[15];
  const float* fc_b     = (const float*)d_in[16];
  const float* h_init   = (const float*)d_in[17];
  float* logits = (float*)d_out;

  char* ws = (char*)d_ws;
  size_t off = 0;
  auto alloc = [&](size_t bytes) { char* p = ws + off; off = (off + bytes + 255) & ~(size_t)255; return p; };
  u16* in1b  = (u16*)alloc(33812480);  // conv1 out bf16 (32,32,254,65)
  u16* hbf   = (u16*)alloc(4352000);   // h bf16 (4000,544)
  float* xge = (float*)alloc(6144000); // enc xg (4000,384)
  u32* ehb_k = (u32*)alloc(1024000);   // eh f16 k-pairs (32,64,125)
  u32* ehb_t = (u32*)alloc(1048576);   // eh f16 t-pairs (32,128,64)
  float* xgd = (float*)alloc(6242304); // dec xg (4064,384)
  u16* adec  = (u16*)alloc(260096);    // emb gather (4064,32)
  u16* outb  = (u16*)alloc(1048576);   // decoder out bf16 (4096,128)
  u32* wT2e  = (u32*)alloc(98304);
  u32* wT2d  = (u32*)alloc(98304);
  u16* w1b   = (u16*)alloc(10240);
  u16* w2b   = (u16*)alloc(327680);
  u16* wihb  = (u16*)alloc(417792);
  u16* dwihb = (u16*)alloc(24576);
  u16* fcwb  = (u16*)alloc(1048576);

  hipFuncSetAttribute((const void*)conv2_k, hipFuncAttributeMaxDynamicSharedMemorySize, 145792);
  hipFuncSetAttribute((const void*)dec_k,   hipFuncAttributeMaxDynamicSharedMemorySize, 66848);

  prep_k<<<4272, 256, 0, stream>>>(rnn_w_hh, dec_w_hh, conv1_w, conv2_w, rnn_w_ih,
                                   dec_w_ih, fc_w, emb, y,
                                   wT2e, wT2d, w1b, w2b, wihb, dwihb, fcwb, adec);
  conv1_k<<<512, 256, 0, stream>>>(x, w1b, conv1_b, in1b);
  conv2_k<<<512, 256, 145792, stream>>>(in1b, w2b, conv2_b, hbf);
  gemm_k<<<dim3(63, 6), 256, 0, stream>>>(hbf, wihb, rnn_b_ih, xge, 4000, 384, 544);
  gemm_k<<<dim3(64, 6), 256, 0, stream>>>(adec, dwihb, dec_b_ih, xgd, 4064, 384, 32);
  enc_k<<<32, 128, 0, stream>>>(wT2e, xge, rnn_b_hh, (u16*)ehb_k, (u16*)ehb_t);
  dec_k<<<32, 128, 66848, stream>>>(wT2d, ehb_k, ehb_t, xgd, dec_b_hh, h_init, outb);
  gemm_k<<<dim3(64, 64), 256, 0, stream>>>(outb, fcwb, fc_b, logits, 4096, 4096, 128);
}

// Round 4
// 739.331 us; speedup vs baseline: 1.9671x; 1.0882x over previous
//
#include <hip/hip_runtime.h>
#include <stdint.h>

typedef unsigned short u16;
typedef uint32_t u32;

typedef __bf16 bf16x8 __attribute__((ext_vector_type(8)));
typedef float f32x4 __attribute__((ext_vector_type(4)));
typedef _Float16 h2v __attribute__((ext_vector_type(2)));

union B8 { uint4 q; u32 u[4]; bf16x8 v; };

__device__ __forceinline__ u16 f2bf(float f) {
  u32 u = __float_as_uint(f);
  u32 r = (u + 0x7fffu + ((u >> 16) & 1u)) >> 16;
  return (u16)r;
}
__device__ __forceinline__ u16 f2h(float f) {
  union { _Float16 h; u16 u; } v; v.h = (_Float16)f; return v.u;
}
__device__ __forceinline__ float dot2h(u32 a, u32 b, float c) {
  union U { u32 u; h2v v; } A, B; A.u = a; B.u = b;
  return __builtin_amdgcn_fdot2(A.v, B.v, c, false);
}
__device__ __forceinline__ float sigf(float x) { return 1.f / (1.f + __expf(-x)); }
__device__ __forceinline__ float tanhf_fast(float x) {
  x = fminf(fmaxf(x, -15.f), 15.f);
  float e = __expf(2.f * x);
  return (e - 1.f) / (e + 1.f);
}

// ---------------- prep: pack/convert all weights ----------------
__global__ __launch_bounds__(256) void prep_k(
    const float* rnn_w_hh, const float* dec_w_hh, const float* conv1_w,
    const float* conv2_w, const float* rnn_w_ih, const float* dec_w_ih,
    const float* fc_w, const float* emb, const int* y,
    u32* wT2e, u32* wT2d, u16* w1b, u16* w2b, u16* wihb, u16* dwihb,
    u16* fcwb, u16* adec)
{
  int e = blockIdx.x * 256 + threadIdx.x;
  const int S0 = 24576, S1 = 24576, S2 = 5120, S3 = 163840, S4 = 208896,
            S5 = 12288, S6 = 524288, S7 = 130048;
  if (e < S0) { int g = e >> 6, k2 = e & 63;   // row-major [g][64], f16 pairs
    wT2e[e] = (u32)f2h(rnn_w_hh[g*128 + 2*k2]) | ((u32)f2h(rnn_w_hh[g*128 + 2*k2 + 1]) << 16);
    return; }
  e -= S0;
  if (e < S1) { int g = e >> 6, k2 = e & 63;
    wT2d[e] = (u32)f2h(dec_w_hh[g*128 + 2*k2]) | ((u32)f2h(dec_w_hh[g*128 + 2*k2 + 1]) << 16);
    return; }
  e -= S1;
  if (e < S2) { int kh = e >> 10, c = (e >> 5) & 31, kw = e & 31;
    w1b[e] = f2bf(conv1_w[c*160 + kh*32 + kw]); return; }
  e -= S2;
  if (e < S3) { int kt = e >> 10, c = (e >> 5) & 31, kw = e & 31;
    int ic = kt / 5, kh = kt - ic * 5;
    w2b[e] = f2bf(conv2_w[((c*32 + ic)*5 + kh)*32 + kw]); return; }
  e -= S3;
  if (e < S4) { wihb[e] = f2bf(rnn_w_ih[e]); return; }
  e -= S4;
  if (e < S5) { dwihb[e] = f2bf(dec_w_ih[e]); return; }
  e -= S5;
  if (e < S6) { fcwb[e] = f2bf(fc_w[e]); return; }
  e -= S6;
  if (e < S7) { int m = e >> 5, k = e & 31;
    int b = m / 127, t = m - b * 127;
    adec[e] = f2bf(emb[y[b*128 + t]*32 + k]); return; }
}

// ---------------- conv1: (32,1,512,161) -> (32,32,254,65), MFMA ----------------
__global__ __launch_bounds__(256) void conv1_k(const float* x, const u16* w1b,
                                               const float* c1b, u16* in1b)
{
  __shared__ __align__(16) u16 slab[35 * 162];
  __shared__ __align__(16) u16 wl[5120];
  int b = blockIdx.x >> 4;
  int oh0 = (blockIdx.x & 15) * 16;
  int ih0 = oh0 * 2;
  for (int e = threadIdx.x; e < 35 * 161; e += 256) {
    int r = e / 161, iw = e - r * 161;
    int ih = ih0 + r;
    float v = (ih < 512) ? x[(b*512 + ih)*161 + iw] : 0.f;
    slab[r*162 + iw] = f2bf(v);
  }
  for (int e = threadIdx.x; e < 5120; e += 256) wl[e] = w1b[e];
  __syncthreads();
  int lane = threadIdx.x & 63, wid = threadIdx.x >> 6;
  int lrow = lane & 15, lk = (lane >> 4) * 8;
  B8 bw[5][2];
  #pragma unroll
  for (int kt = 0; kt < 5; kt++)
    #pragma unroll
    for (int ct = 0; ct < 2; ct++)
      bw[kt][ct].q = *(const uint4*)&wl[(kt*32 + ct*16 + lrow)*32 + lk];
  float bias0 = c1b[lrow], bias1 = c1b[16 + lrow];
  for (int mt = wid; mt < 65; mt += 4) {
    int m = mt * 16 + lrow;
    int ohl = m / 65, ow = m - ohl * 65;
    int ro = ohl * 324 + ow * 2 + lk;
    f32x4 a0, a1;
    #pragma unroll
    for (int i = 0; i < 4; i++) { a0[i] = 0.f; a1[i] = 0.f; }
    #pragma unroll
    for (int kt = 0; kt < 5; kt++) {
      B8 af;
      const u32* p = (const u32*)&slab[ro + kt * 162];
      af.u[0] = p[0]; af.u[1] = p[1]; af.u[2] = p[2]; af.u[3] = p[3];
      a0 = __builtin_amdgcn_mfma_f32_16x16x32_bf16(af.v, bw[kt][0].v, a0, 0, 0, 0);
      a1 = __builtin_amdgcn_mfma_f32_16x16x32_bf16(af.v, bw[kt][1].v, a1, 0, 0, 0);
    }
    int rb = mt * 16 + (lane >> 4) * 4;
    #pragma unroll
    for (int i = 0; i < 4; i++) {
      int mr = rb + i;
      int ohl2 = mr / 65, ow2 = mr - ohl2 * 65;
      int oh = oh0 + ohl2;
      if (oh < 254) {
        float v0 = fmaxf(a0[i] + bias0, 0.f);
        float v1 = fmaxf(a1[i] + bias1, 0.f);
        in1b[((b*32 + lrow)*254 + oh)*65 + ow2] = f2bf(v0);
        in1b[((b*32 + 16 + lrow)*254 + oh)*65 + ow2] = f2bf(v1);
      }
    }
  }
}

// ---------------- conv2: (32,32,254,65) -> h (32,125,544) bf16, MFMA ----------------
__global__ __launch_bounds__(256) void conv2_k(const u16* in1b, const u16* w2b,
                                               const float* c2b, u16* hbf)
{
  extern __shared__ char smem[];
  u16* slab = (u16*)smem;              // [32][19][66]  = 80256 B
  u16* wl = (u16*)(smem + 80256);      // [32][32][32]  = 65536 B
  int b = blockIdx.x >> 4;
  int oh0 = (blockIdx.x & 15) * 8;
  int ih0 = oh0 * 2;
  for (int e = threadIdx.x; e < 32 * 19 * 65; e += 256) {
    int ic = e / (19 * 65);
    int rem = e - ic * (19 * 65);
    int r = rem / 65, iw = rem - r * 65;
    int ih = ih0 + r;
    u16 v = (ih < 254) ? in1b[((b*32 + ic)*254 + ih)*65 + iw] : (u16)0;
    slab[(ic*19 + r)*66 + iw] = v;
  }
  int lane = threadIdx.x & 63, wid = threadIdx.x >> 6;
  int lrow = lane & 15, lk = (lane >> 4) * 8;
  int ohl_[3], ow_[3];
  #pragma unroll
  for (int q = 0; q < 3; q++) {
    int mt = (q == 2) ? 8 : (wid + q * 4);
    int m = mt * 16 + lrow;
    if (m > 135) m = 0;
    ohl_[q] = m / 17; ow_[q] = m - ohl_[q] * 17;
  }
  f32x4 acc[3][2];
  #pragma unroll
  for (int q = 0; q < 3; q++)
    #pragma unroll
    for (int ct = 0; ct < 2; ct++)
      #pragma unroll
      for (int i = 0; i < 4; i++) acc[q][ct][i] = 0.f;

  for (int ph = 0; ph < 5; ph++) {
    __syncthreads();
    for (int e = threadIdx.x; e < 32768; e += 256) wl[e] = w2b[ph * 32768 + e];
    __syncthreads();
    for (int ktl = 0; ktl < 32; ktl++) {
      int ktg = ph * 32 + ktl;
      int ic = ktg / 5, kh = ktg - ic * 5;
      B8 fb0, fb1;
      fb0.q = *(const uint4*)&wl[(ktl*32 + lrow)*32 + lk];
      fb1.q = *(const uint4*)&wl[(ktl*32 + 16 + lrow)*32 + lk];
      int base = (ic * 19 + kh) * 66 + lk;
      #pragma unroll
      for (int q = 0; q < 3; q++) {
        if (q == 2 && wid != 0) break;
        B8 af;
        const u32* p = (const u32*)&slab[base + ohl_[q] * 132 + ow_[q] * 2];
        af.u[0] = p[0]; af.u[1] = p[1]; af.u[2] = p[2]; af.u[3] = p[3];
        acc[q][0] = __builtin_amdgcn_mfma_f32_16x16x32_bf16(af.v, fb0.v, acc[q][0], 0, 0, 0);
        acc[q][1] = __builtin_amdgcn_mfma_f32_16x16x32_bf16(af.v, fb1.v, acc[q][1], 0, 0, 0);
      }
    }
  }
  #pragma unroll
  for (int q = 0; q < 3; q++) {
    if (q == 2 && wid != 0) break;
    int mt = (q == 2) ? 8 : (wid + q * 4);
    int rb = mt * 16 + (lane >> 4) * 4;
    #pragma unroll
    for (int ct = 0; ct < 2; ct++) {
      int c = ct * 16 + lrow;
      float bias = c2b[c];
      #pragma unroll
      for (int i = 0; i < 4; i++) {
        int mr = rb + i;
        if (mr < 136) {
          int ohl = mr / 17, ow = mr - ohl * 17;
          int oh = oh0 + ohl;
          if (oh < 125) {
            float v = fmaxf(acc[q][ct][i] + bias, 0.f);
            hbf[(b*125 + oh)*544 + ow*32 + c] = f2bf(v);
          }
        }
      }
    }
  }
}

// ---------------- generic bf16 MFMA GEMM: C = A(MxK) * B(NxK)^T + bias ----------------
__global__ __launch_bounds__(256) void gemm_k(const u16* A, const u16* Bw,
                                              const float* bias, float* C,
                                              int M, int N, int K)
{
  __shared__ __align__(16) u16 As[64 * 32];
  __shared__ __align__(16) u16 Bs[64 * 32];
  int m0 = blockIdx.x * 64, n0 = blockIdx.y * 64;
  int tid = threadIdx.x;
  int lane = tid & 63, wid = tid >> 6;
  int lrow = lane & 15, lk = (lane >> 4) * 8;
  int sr = tid >> 2, sc8 = (tid & 3) * 8;
  f32x4 acc[4];
  #pragma unroll
  for (int nt = 0; nt < 4; nt++)
    #pragma unroll
    for (int i = 0; i < 4; i++) acc[nt][i] = 0.f;
  int nkt = K >> 5;
  for (int kt = 0; kt < nkt; kt++) {
    __syncthreads();
    uint4 va = make_uint4(0u, 0u, 0u, 0u);
    int arow = m0 + sr;
    if (arow < M) va = *(const uint4*)&A[arow * K + kt * 32 + sc8];
    *(uint4*)&As[sr * 32 + sc8] = va;
    uint4 vb = *(const uint4*)&Bw[(n0 + sr) * K + kt * 32 + sc8];
    *(uint4*)&Bs[sr * 32 + sc8] = vb;
    __syncthreads();
    B8 af; af.q = *(const uint4*)&As[(wid * 16 + lrow) * 32 + lk];
    #pragma unroll
    for (int nt = 0; nt < 4; nt++) {
      B8 bb; bb.q = *(const uint4*)&Bs[(nt * 16 + lrow) * 32 + lk];
      acc[nt] = __builtin_amdgcn_mfma_f32_16x16x32_bf16(af.v, bb.v, acc[nt], 0, 0, 0);
    }
  }
  #pragma unroll
  for (int nt = 0; nt < 4; nt++) {
    int col = n0 + nt * 16 + lrow;
    float bv = bias[col];
    #pragma unroll
    for (int i = 0; i < 4; i++) {
      int row = m0 + wid * 16 + (lane >> 4) * 4 + i;
      if (row < M) C[row * N + col] = acc[nt][i] + bv;
    }
  }
}

// ---------------- encoder GRU scan: 16 blocks, 512 thr, 2 batches, K-split ----------------
__global__ __launch_bounds__(512, 2) void enc_k(const u32* wT2, const float* xg,
                                                const float* bhh_g, u16* ehk, u16* eht)
{
  __shared__ __align__(16) u32 hp[2][64];
  __shared__ float hg[2][384];
  int tid = threadIdx.x;
  int g = tid >> 8, tb = tid & 255, kh = tb >> 7, t = tb & 127;
  int b = blockIdx.x * 2 + g;
  u32 w0[32], w1[32], w2[32];
  {
    const uint4* p0 = (const uint4*)(wT2 + ((size_t)t) * 64 + kh * 32);
    const uint4* p1 = (const uint4*)(wT2 + ((size_t)(128 + t)) * 64 + kh * 32);
    const uint4* p2 = (const uint4*)(wT2 + ((size_t)(256 + t)) * 64 + kh * 32);
    #pragma unroll
    for (int j = 0; j < 8; j++) {
      uint4 q0 = p0[j]; w0[4*j] = q0.x; w0[4*j+1] = q0.y; w0[4*j+2] = q0.z; w0[4*j+3] = q0.w;
      uint4 q1 = p1[j]; w1[4*j] = q1.x; w1[4*j+1] = q1.y; w1[4*j+2] = q1.z; w1[4*j+3] = q1.w;
      uint4 q2 = p2[j]; w2[4*j] = q2.x; w2[4*j+1] = q2.y; w2[4*j+2] = q2.z; w2[4*j+3] = q2.w;
    }
  }
  float b0 = 0.f, b1 = 0.f, b2 = 0.f, xr0 = 0.f, xr1 = 0.f, xr2 = 0.f, hreg = 0.f;
  if (kh == 0) {
    b0 = bhh_g[t]; b1 = bhh_g[128 + t]; b2 = bhh_g[256 + t];
    const float* xp = &xg[(size_t)b * 125 * 384];
    xr0 = xp[t]; xr1 = xp[128 + t]; xr2 = xp[256 + t];
    ((u16*)&hp[g][0])[t] = 0;
  }
  __syncthreads();
  for (int tt = 0; tt < 125; tt++) {
    const u32* hb = &hp[g][kh * 32];
    float r0 = 0.f, r1 = 0.f, z0 = 0.f, z1 = 0.f, n0 = 0.f, n1 = 0.f;
    #pragma unroll
    for (int j = 0; j < 8; j++) {
      uint4 hv = *(const uint4*)&hb[4*j];
      r0 = dot2h(w0[4*j+0], hv.x, r0); r1 = dot2h(w0[4*j+1], hv.y, r1);
      r0 = dot2h(w0[4*j+2], hv.z, r0); r1 = dot2h(w0[4*j+3], hv.w, r1);
      z0 = dot2h(w1[4*j+0], hv.x, z0); z1 = dot2h(w1[4*j+1], hv.y, z1);
      z0 = dot2h(w1[4*j+2], hv.z, z0); z1 = dot2h(w1[4*j+3], hv.w, z1);
      n0 = dot2h(w2[4*j+0], hv.x, n0); n1 = dot2h(w2[4*j+1], hv.y, n1);
      n0 = dot2h(w2[4*j+2], hv.z, n0); n1 = dot2h(w2[4*j+3], hv.w, n1);
    }
    float pr = r0 + r1, pz = z0 + z1, pn = n0 + n1;
    if (kh) { hg[g][t] = pr; hg[g][128 + t] = pz; hg[g][256 + t] = pn; }
    __syncthreads();
    if (kh == 0) {
      float r = sigf(xr0 + pr + hg[g][t] + b0);
      float z = sigf(xr1 + pz + hg[g][128 + t] + b1);
      float n = tanhf_fast(xr2 + r * (pn + hg[g][256 + t] + b2));
      hreg = (1.f - z) * n + z * hreg;
      u16 hv = f2h(hreg);
      ((u16*)&hp[g][0])[t] = hv;
      ehk[((size_t)(b*64 + (t >> 1)) * 125 + tt) * 2 + (t & 1)] = hv;
      eht[((size_t)(b*128 + t)) * 128 + tt] = hv;
      if (tt + 1 < 125) {
        const float* xq = &xg[((size_t)b * 125 + tt + 1) * 384];
        xr0 = xq[t]; xr1 = xq[128 + t]; xr2 = xq[256 + t];
      }
    }
    __syncthreads();
  }
  if (kh == 0) {
    size_t rb = ((size_t)(b*128 + t)) * 128;
    eht[rb + 125] = 0; eht[rb + 126] = 0; eht[rb + 127] = 0;
  }
}

// ---------------- decoder GRU + attention: 16 blocks, 512 thr, 2 batches, K-split ----------------
// LDS per batch (34832 B): elK 32000 | hgP 1536 | ctxB 512 | hxA 256 | hxB 256 | scp 256 | red 16
__global__ __launch_bounds__(512, 2) void dec_k(const u32* wT2, const u32* ehk_g,
                                                const u32* eht_g, const float* xgd,
                                                const float* bhh_g, const float* h_init,
                                                u16* outb)
{
  extern __shared__ char sm[];
  int tid = threadIdx.x;
  int g = tid >> 8, tb = tid & 255, kh = tb >> 7, t = tb & 127;
  int b = blockIdx.x * 2 + g;
  char* base = sm + (size_t)g * 34832;
  u32* elK   = (u32*)base;
  float* hgP = (float*)(base + 32000);
  float* ctxB= (float*)(base + 33536);
  u32* hxA   = (u32*)(base + 34048);
  u32* hxB   = (u32*)(base + 34304);
  u32* scp   = (u32*)(base + 34560);
  float* red = (float*)(base + 34816);

  u32 w0[32], w1[32], w2[32];
  {
    const uint4* p0 = (const uint4*)(wT2 + ((size_t)t) * 64 + kh * 32);
    const uint4* p1 = (const uint4*)(wT2 + ((size_t)(128 + t)) * 64 + kh * 32);
    const uint4* p2 = (const uint4*)(wT2 + ((size_t)(256 + t)) * 64 + kh * 32);
    #pragma unroll
    for (int j = 0; j < 8; j++) {
      uint4 q0 = p0[j]; w0[4*j] = q0.x; w0[4*j+1] = q0.y; w0[4*j+2] = q0.z; w0[4*j+3] = q0.w;
      uint4 q1 = p1[j]; w1[4*j] = q1.x; w1[4*j+1] = q1.y; w1[4*j+2] = q1.z; w1[4*j+3] = q1.w;
      uint4 q2 = p2[j]; w2[4*j] = q2.x; w2[4*j+1] = q2.y; w2[4*j+2] = q2.z; w2[4*j+3] = q2.w;
    }
  }
  // eh row (context operand, step-constant): 32 u32 = this thread's t-pair half
  u32 rowr[32];
  {
    const uint4* rp = (const uint4*)(eht_g + (size_t)b * 8192 + (size_t)t * 64 + kh * 32);
    #pragma unroll
    for (int j = 0; j < 8; j++) {
      uint4 q = rp[j]; rowr[4*j] = q.x; rowr[4*j+1] = q.y; rowr[4*j+2] = q.z; rowr[4*j+3] = q.w;
    }
  }
  for (int e = tb; e < 8000; e += 256) elK[e] = ehk_g[(size_t)b * 8000 + e];
  float b0 = 0.f, b1 = 0.f, b2 = 0.f, xr0 = 0.f, xr1 = 0.f, xr2 = 0.f;
  float hxf = 0.f, hxg = 0.f;
  if (kh == 0) {
    b0 = bhh_g[t]; b1 = bhh_g[128 + t]; b2 = bhh_g[256 + t];
    hxf = h_init[t];
    const float* xp = &xgd[(size_t)b * 127 * 384];
    xr0 = xp[t]; xr1 = xp[128 + t]; xr2 = xp[256 + t];
  }
  __syncthreads();

  for (int step = 0; step < 128; step++) {
    if (step > 0) {
      // ---- S0: GRU half-K dots ----
      const u32* hb = hxB + kh * 32;
      float r0 = 0.f, r1 = 0.f, z0 = 0.f, z1 = 0.f, n0 = 0.f, n1 = 0.f;
      #pragma unroll
      for (int j = 0; j < 8; j++) {
        uint4 hv = *(const uint4*)&hb[4*j];
        r0 = dot2h(w0[4*j+0], hv.x, r0); r1 = dot2h(w0[4*j+1], hv.y, r1);
        r0 = dot2h(w0[4*j+2], hv.z, r0); r1 = dot2h(w0[4*j+3], hv.w, r1);
        z0 = dot2h(w1[4*j+0], hv.x, z0); z1 = dot2h(w1[4*j+1], hv.y, z1);
        z0 = dot2h(w1[4*j+2], hv.z, z0); z1 = dot2h(w1[4*j+3], hv.w, z1);
        n0 = dot2h(w2[4*j+0], hv.x, n0); n1 = dot2h(w2[4*j+1], hv.y, n1);
        n0 = dot2h(w2[4*j+2], hv.z, n0); n1 = dot2h(w2[4*j+3], hv.w, n1);
      }
      float pr = r0 + r1, pz = z0 + z1, pn = n0 + n1;
      if (kh) { hgP[t] = pr; hgP[128 + t] = pz; hgP[256 + t] = pn; }
      __syncthreads();                       // bar1
      if (kh == 0) {
        float r = sigf(xr0 + pr + hgP[t] + b0);
        float z = sigf(xr1 + pz + hgP[128 + t] + b1);
        float n = tanhf_fast(xr2 + r * (pn + hgP[256 + t] + b2));
        hxg = (1.f - z) * n + z * hxf;
        ((u16*)hxA)[t] = f2h(hxg);
        if (step < 127) {
          const float* xq = &xgd[((size_t)b * 127 + step) * 384];
          xr0 = xq[t]; xr1 = xq[128 + t]; xr2 = xq[256 + t];
        }
      }
      __syncthreads();                       // bar2
    } else {
      if (kh == 0) { hxg = hxf; ((u16*)hxA)[t] = f2h(hxg); }
      __syncthreads();                       // bar2
    }
    // ---- S2: scores (kh0 only; t = time index) ----
    if (kh == 0) {
      float s0 = 0.f, s1 = 0.f, s2 = 0.f, s3 = 0.f;
      #pragma unroll
      for (int j = 0; j < 16; j++) {
        uint4 aw = *(const uint4*)&hxA[4*j];
        s0 = dot2h(elK[(4*j+0)*125 + t], aw.x, s0);
        s1 = dot2h(elK[(4*j+1)*125 + t], aw.y, s1);
        s2 = dot2h(elK[(4*j+2)*125 + t], aw.z, s2);
        s3 = dot2h(elK[(4*j+3)*125 + t], aw.w, s3);
      }
      float s = (t < 125) ? ((s0 + s1) + (s2 + s3)) : -1e30f;
      float mw = s;
      #pragma unroll
      for (int o = 32; o > 0; o >>= 1) mw = fmaxf(mw, __shfl_xor(mw, o));
      float ev = (t < 125) ? __expf(s - mw) : 0.f;
      float sw = ev;
      #pragma unroll
      for (int o = 32; o > 0; o >>= 1) sw += __shfl_xor(sw, o);
      ((u16*)scp)[t] = f2h(ev);
      if ((tb & 63) == 0) { int wv = tb >> 6; red[wv*2] = mw; red[wv*2 + 1] = sw; }
    }
    __syncthreads();                         // bar3
    // ---- S3: context half-T dots (all threads) ----
    float m0r = red[0], S0r = red[1], m1r = red[2], S1r = red[3];
    float M = fmaxf(m0r, m1r);
    float f0 = __expf(m0r - M), f1 = __expf(m1r - M);
    float inv = 1.f / (f0 * S0r + f1 * S1r);
    const u32* sp = scp + kh * 32;
    float c0 = 0.f, c1 = 0.f;
    #pragma unroll
    for (int j = 0; j < 8; j++) {
      uint4 sw4 = *(const uint4*)&sp[4*j];
      c0 = dot2h(rowr[4*j+0], sw4.x, c0); c1 = dot2h(rowr[4*j+1], sw4.y, c1);
      c0 = dot2h(rowr[4*j+2], sw4.z, c0); c1 = dot2h(rowr[4*j+3], sw4.w, c1);
    }
    if (kh) ctxB[t] = c0 + c1;
    __syncthreads();                         // bar4
    if (kh == 0) {
      float ctx = ((c0 + c1) * f0 + ctxB[t] * f1) * inv;
      hxf = hxg + ctx;
      outb[((size_t)(b * 128) + step) * 128 + t] = f2bf(hxf);
      ((u16*)hxB)[t] = f2h(hxf);
    }
    __syncthreads();                         // bar5
  }
}

// ---------------- host launch ----------------
extern "C" void kernel_launch(void* const* d_in, const int* in_sizes, int n_in,
                              void* d_out, int out_size, void* d_ws, size_t ws_size,
                              hipStream_t stream)
{
  const float* x        = (const float*)d_in[0];
  const int*   y        = (const int*)d_in[1];
  const float* conv1_w  = (const float*)d_in[2];
  const float* conv1_b  = (const float*)d_in[3];
  const float* conv2_w  = (const float*)d_in[4];
  const float* conv2_b  = (const float*)d_in[5];
  const float* rnn_w_ih = (const float*)d_in[6];
  const float* rnn_w_hh = (const float*)d_in[7];
  const float* rnn_b_ih = (const float*)d_in[8];
  const float* rnn_b_hh = (const float*)d_in[9];
  const float* emb      = (const float*)d_in[10];
  const float* dec_w_ih = (const float*)d_in[11];
  const float* dec_w_hh = (const float*)d_in[12];
  const float* dec_b_ih = (const float*)d_in[13];
  const float* dec_b_hh = (const float*)d_in[14];
  const float* fc_w     = (const float*)d_in[15];
  const float* fc_b     = (const float*)d_in[16];
  const float* h_init   = (const float*)d_in[17];
  float* logits = (float*)d_out;

  char* ws = (char*)d_ws;
  size_t off = 0;
  auto alloc = [&](size_t bytes) { char* p = ws + off; off = (off + bytes + 255) & ~(size_t)255; return p; };
  u16* in1b  = (u16*)alloc(33812480);  // conv1 out bf16 (32,32,254,65)
  u16* hbf   = (u16*)alloc(4352000);   // h bf16 (4000,544)
  float* xge = (float*)alloc(6144000); // enc xg (4000,384)
  u32* ehb_k = (u32*)alloc(1024000);   // eh f16 k-pairs (32,64,125)
  u32* ehb_t = (u32*)alloc(1048576);   // eh f16 t-pairs (32,128,64)
  float* xgd = (float*)alloc(6242304); // dec xg (4064,384)
  u16* adec  = (u16*)alloc(260096);    // emb gather (4064,32)
  u16* outb  = (u16*)alloc(1048576);   // decoder out bf16 (4096,128)
  u32* wT2e  = (u32*)alloc(98304);
  u32* wT2d  = (u32*)alloc(98304);
  u16* w1b   = (u16*)alloc(10240);
  u16* w2b   = (u16*)alloc(327680);
  u16* wihb  = (u16*)alloc(417792);
  u16* dwihb = (u16*)alloc(24576);
  u16* fcwb  = (u16*)alloc(1048576);

  hipFuncSetAttribute((const void*)conv2_k, hipFuncAttributeMaxDynamicSharedMemorySize, 145792);
  hipFuncSetAttribute((const void*)dec_k,   hipFuncAttributeMaxDynamicSharedMemorySize, 69664);

  prep_k<<<4272, 256, 0, stream>>>(rnn_w_hh, dec_w_hh, conv1_w, conv2_w, rnn_w_ih,
                                   dec_w_ih, fc_w, emb, y,
                                   wT2e, wT2d, w1b, w2b, wihb, dwihb, fcwb, adec);
  conv1_k<<<512, 256, 0, stream>>>(x, w1b, conv1_b, in1b);
  conv2_k<<<512, 256, 145792, stream>>>(in1b, w2b, conv2_b, hbf);
  gemm_k<<<dim3(63, 6), 256, 0, stream>>>(hbf, wihb, rnn_b_ih, xge, 4000, 384, 544);
  gemm_k<<<dim3(64, 6), 256, 0, stream>>>(adec, dwihb, dec_b_ih, xgd, 4064, 384, 32);
  enc_k<<<16, 512, 0, stream>>>(wT2e, xge, rnn_b_hh, (u16*)ehb_k, (u16*)ehb_t);
  dec_k<<<16, 512, 69664, stream>>>(wT2d, ehb_k, ehb_t, xgd, dec_b_hh, h_init, outb);
  gemm_k<<<dim3(64, 64), 256, 0, stream>>>(outb, fcwb, fc_b, logits, 4096, 4096, 128);
}